// Round 7
// baseline (338.800 us; speedup 1.0000x reference)
//
#include <hip/hip_runtime.h>

// ---------------------------------------------------------------------------
// MaskedSuperAttention (agent attention), B=4 N=16384 C=512 H=8 HD=64 NA=32
//   k_w_t_p      : Wproj f32 [k][n] -> Wpt bf16 [n][k] row-major (for k_avp)
//   k_w_tile     : Wq/Wk/Wv -> wtl tiled-swizzled (for k_qkv gload_lds)
//   k_pack_a     : agent_tokens -> abf [h][32][64] bf16
//   k_qkv        : FUSED cvt: A reg-staged from x f32 (issue-early/write-late),
//                  B gl2lds; 512 thr / 8 waves (2m x 4n), 40KB LDS, 2-barrier.
//                  Writes Q,K (row) and V (transposed). No xt buffer.
//   k_agent_part : split-K flash partials ; grid 2048
//   k_agent_comb : merge partials -> agent_v bf16
//   k_avp        : AVP = agent_v @ Wproj -> AVPt TILED
//   k_qattn      : MFMA softmax(q.a*scale) -> Qattn TILED (standalone, R4 ver)
//   k_out        : out = (Qattn @ AVPt) * keymask ; gload_lds staging
// Tiled layout: tile = 128 rows x 64 k (16 KiB); byte(row,c8) =
//   base + row*128 + ((c8 ^ (row&7))<<4)   (c8 = 16B slot, 0..7)
// R7: deleted k_cvt_x (61us, was AT roofline -> delete its traffic instead);
// k_qkv ingests x f32 directly. R6's fused q-attn epilogue reverted (+30us
// serialized; k_qattn standalone is cheaper).
// ---------------------------------------------------------------------------

typedef float  f32x4   __attribute__((ext_vector_type(4)));
typedef short  bf16x8  __attribute__((ext_vector_type(8)));
typedef unsigned short u16x4 __attribute__((ext_vector_type(4)));
typedef unsigned short u16x8 __attribute__((ext_vector_type(8)));

#define MFMA16(a, b, c) __builtin_amdgcn_mfma_f32_16x16x32_bf16((a), (b), (c), 0, 0, 0)

__device__ __forceinline__ unsigned short f2bf(float f) {
    unsigned u = __builtin_bit_cast(unsigned, f);
    u += 0x7FFFu + ((u >> 16) & 1u);        // RTNE
    return (unsigned short)(u >> 16);
}
__device__ __forceinline__ float bf2f(unsigned short h) {
    unsigned u = ((unsigned)h) << 16;
    return __builtin_bit_cast(float, u);
}
__device__ __forceinline__ void gl2lds16(const void* g, void* l) {
    __builtin_amdgcn_global_load_lds(
        (const __attribute__((address_space(1))) unsigned int*)g,
        (__attribute__((address_space(3))) unsigned int*)l, 16, 0, 0);
}

// ------------------------------- k_w_t_p ------------------------------------
__global__ __launch_bounds__(256) void k_w_t_p(const float* __restrict__ Wp,
                                               unsigned short* __restrict__ Wpt) {
    __shared__ float t[32][33];
    const int k0 = blockIdx.y * 32, n0 = blockIdx.x * 32;
#pragma unroll
    for (int j = 0; j < 4; ++j) {
        int i = threadIdx.x + 256 * j;
        int ky = i >> 5, nx = i & 31;
        t[ky][nx] = Wp[(size_t)(k0 + ky) * 512 + n0 + nx];
    }
    __syncthreads();
#pragma unroll
    for (int j = 0; j < 4; ++j) {
        int i = threadIdx.x + 256 * j;
        int ny = i >> 5, kx = i & 31;
        Wpt[(size_t)(n0 + ny) * 512 + k0 + kx] = f2bf(t[kx][ny]);
    }
}

// ------------------------------- k_w_tile -----------------------------------
__global__ __launch_bounds__(256) void k_w_tile(const float* __restrict__ Wq,
                                                const float* __restrict__ Wk,
                                                const float* __restrict__ Wv,
                                                unsigned char* __restrict__ wtl) {
    const int ks = blockIdx.x, nt = blockIdx.y, mat = blockIdx.z;
    const float* src = (mat == 0) ? Wq : (mat == 1) ? Wk : Wv;
    const size_t dbase = ((size_t)((nt * 8 + ks) * 3 + mat)) * 8192;
    const int row = threadIdx.x & 63;
#pragma unroll
    for (int cc = 0; cc < 2; ++cc) {
        int c = (threadIdx.x >> 6) + cc * 4;
        u16x8 o;
#pragma unroll
        for (int j = 0; j < 8; ++j)
            o[j] = f2bf(src[(size_t)(ks * 64 + c * 8 + j) * 512 + nt * 64 + row]);
        *(u16x8*)(wtl + dbase + row * 128 + ((c ^ (row & 7)) << 4)) = o;
    }
}

// ------------------------------- k_pack_a -----------------------------------
__global__ __launch_bounds__(256) void k_pack_a(const float* __restrict__ at,
                                                unsigned short* __restrict__ abf) {
    int idx = threadIdx.x + blockIdx.x * 256;       // 0..16383
    int h = idx >> 11, ag = (idx >> 6) & 31, d = idx & 63;
    abf[idx] = f2bf(at[ag * 512 + h * 64 + d]);
}

// ------------------------------- k_qkv ---------------------------------------
// BM=128, BN=192 (Q64,K64,V64), BK=64. 512 thr / 8 waves (wm=wid>>2, wn=wid&3),
// wave tile 64 tok x 48 cols. A reg-staged from x f32 + cvt + swizzled
// ds_write_b128 (next-tile loads issued after barrier 1, consumed after
// barrier 2); B via gl2lds of pre-swizzled wtl. 40KB LDS single-buffer.
// grid 4096 (XCD-swizzled), block 512.
__global__ __launch_bounds__(512) void k_qkv(const float* __restrict__ x,
                                             const unsigned char* __restrict__ wtl,
                                             unsigned short* __restrict__ Qbf,
                                             unsigned short* __restrict__ Kbf,
                                             unsigned short* __restrict__ Vt) {
    __shared__ __align__(16) unsigned char As[16384];
    __shared__ __align__(16) unsigned char Bs[24576];
    const int tid = threadIdx.x, l = tid & 63, wid = tid >> 6;
    const int g = l >> 4, lr = l & 15;
    const int wm = wid >> 2, wn = wid & 3;
    const int dd = blockIdx.x;
    const int nt = (dd >> 3) & 7;
    const int mt = (dd & 7) + ((dd >> 6) << 3);
    const int m0 = mt * 128, n0 = nt * 64;
    const int arow = tid >> 2, aq = tid & 3;        // row 0..127, k-quarter 0..3
    const float* aptr = x + (size_t)(m0 + arow) * 512 + aq * 16;

    f32x4 acc[4][3] = {};
    float4 xr[4];

    // preload A(0): 16 f32 per thread
#pragma unroll
    for (int j = 0; j < 4; ++j) xr[j] = ((const float4*)aptr)[j];

    for (int ks = 0; ks < 8; ++ks) {
        // ---- stage A(ks): cvt f32->bf16, swizzled ds_write_b128 ----
#pragma unroll
        for (int jj = 0; jj < 2; ++jj) {
            u16x8 o;
            o[0] = f2bf(xr[2 * jj].x);     o[1] = f2bf(xr[2 * jj].y);
            o[2] = f2bf(xr[2 * jj].z);     o[3] = f2bf(xr[2 * jj].w);
            o[4] = f2bf(xr[2 * jj + 1].x); o[5] = f2bf(xr[2 * jj + 1].y);
            o[6] = f2bf(xr[2 * jj + 1].z); o[7] = f2bf(xr[2 * jj + 1].w);
            *(u16x8*)(As + arow * 128 + (((aq * 2 + jj) ^ (arow & 7)) << 4)) = o;
        }
        // ---- stage B(ks): gl2lds of pre-swizzled weight trio ----
        const size_t bbase = ((size_t)((nt * 8 + ks) * 3)) * 8192;
#pragma unroll
        for (int i = 0; i < 3; ++i)
            gl2lds16(wtl + bbase + i * 8192 + tid * 16, Bs + i * 8192 + tid * 16);
        __syncthreads();

        // ---- issue-early: A loads for ks+1 (consumed after next barrier) ----
        if (ks < 7) {
            const float* ap = aptr + (ks + 1) * 64;
#pragma unroll
            for (int j = 0; j < 4; ++j) xr[j] = ((const float4*)ap)[j];
        }

        bf16x8 af[4][2];
#pragma unroll
        for (int mf = 0; mf < 4; ++mf) {
            int row = wm * 64 + mf * 16 + lr;
#pragma unroll
            for (int k2 = 0; k2 < 2; ++k2)
                af[mf][k2] = *(const bf16x8*)(As + row * 128 + (((k2 * 4 + g) ^ (row & 7)) << 4));
        }
#pragma unroll
        for (int k2 = 0; k2 < 2; ++k2) {
#pragma unroll
            for (int nf = 0; nf < 3; ++nf) {
                int f = wn * 3 + nf, mat = f >> 2, sub = f & 3;
                int brow = sub * 16 + lr;
                bf16x8 bv = *(const bf16x8*)(Bs + mat * 8192 + brow * 128 +
                                             (((k2 * 4 + g) ^ (brow & 7)) << 4));
#pragma unroll
                for (int mf = 0; mf < 4; ++mf)
                    acc[mf][nf] = MFMA16(af[mf][k2], bv, acc[mf][nf]);
            }
        }
        __syncthreads();
    }

    // ---- epilogue: Q,K row stores; V transposed ----
    const int b = m0 >> 14;
    const int nloc0 = m0 & 16383;
#pragma unroll
    for (int mf = 0; mf < 4; ++mf) {
        int trow = wm * 64 + mf * 16 + g * 4;
#pragma unroll
        for (int nf = 0; nf < 3; ++nf) {
            int f = wn * 3 + nf, mat = f >> 2, sub = f & 3;
            int dc = n0 + sub * 16 + lr;
            if (mat == 0) {
#pragma unroll
                for (int r = 0; r < 4; ++r)
                    Qbf[(size_t)(m0 + trow + r) * 512 + dc] = f2bf(acc[mf][nf][r]);
            } else if (mat == 1) {
#pragma unroll
                for (int r = 0; r < 4; ++r)
                    Kbf[(size_t)(m0 + trow + r) * 512 + dc] = f2bf(acc[mf][nf][r]);
            } else {
                u16x4 vv;
                vv[0] = f2bf(acc[mf][nf][0]); vv[1] = f2bf(acc[mf][nf][1]);
                vv[2] = f2bf(acc[mf][nf][2]); vv[3] = f2bf(acc[mf][nf][3]);
                *(u16x4*)(Vt + ((size_t)(b * 512 + dc)) * 16384 + nloc0 + trow) = vv;
            }
        }
    }
}

// ------------------------------- k_agent_part --------------------------------
// grid (64 chunks, 32 bh), block 256 (4 waves x 64 tokens).
__global__ __launch_bounds__(256) void k_agent_part(const unsigned short* __restrict__ Kbf,
                                                    const unsigned short* __restrict__ Vt,
                                                    const unsigned short* __restrict__ abf,
                                                    const int* __restrict__ mask,
                                                    float* __restrict__ part_pv,
                                                    float* __restrict__ part_ml) {
    __shared__ __align__(16) unsigned char Psm[4][2048];
    __shared__ float avs[4][2048];
    __shared__ float redM[4][32];
    __shared__ float redL[4][32];
    const int tid = threadIdx.x, l = tid & 63, wid = tid >> 6;
    const int g = l >> 4, lr = l & 15;
    const int c = blockIdx.x, bh = blockIdx.y, b = bh >> 3, h = bh & 7;
    const int tok0 = c * 256 + wid * 64;

    bf16x8 af[2][2];
#pragma unroll
    for (int mf = 0; mf < 2; ++mf)
#pragma unroll
        for (int ks = 0; ks < 2; ++ks)
            af[mf][ks] = *(const bf16x8*)(abf + (size_t)h * 2048 + (mf * 16 + lr) * 64 + ks * 32 + g * 8);

    const size_t kbase = (size_t)(b * 16384) * 512 + h * 64;
    const int maskbase = b * 16384;

    f32x4 sc[4][2];
#pragma unroll
    for (int it = 0; it < 4; ++it) {
        int tokn = tok0 + it * 16 + lr;
        const unsigned short* kp = Kbf + kbase + (size_t)tokn * 512;
        bf16x8 b0 = *(const bf16x8*)(kp + g * 8);
        bf16x8 b1 = *(const bf16x8*)(kp + 32 + g * 8);
        int mv = mask[maskbase + tokn];
        f32x4 z = {0.f, 0.f, 0.f, 0.f};
        f32x4 a0 = MFMA16(af[0][0], b0, z); a0 = MFMA16(af[0][1], b1, a0);
        f32x4 a1 = MFMA16(af[1][0], b0, z); a1 = MFMA16(af[1][1], b1, a1);
#pragma unroll
        for (int r = 0; r < 4; ++r) {
            a0[r] = (mv > 0) ? a0[r] * 0.125f : -1.0e9f;
            a1[r] = (mv > 0) ? a1[r] * 0.125f : -1.0e9f;
        }
        sc[it][0] = a0; sc[it][1] = a1;
    }

    float mx[8];
#pragma unroll
    for (int s = 0; s < 8; ++s) {
        float m = sc[0][s >> 2][s & 3];
        m = fmaxf(m, sc[1][s >> 2][s & 3]);
        m = fmaxf(m, sc[2][s >> 2][s & 3]);
        m = fmaxf(m, sc[3][s >> 2][s & 3]);
#pragma unroll
        for (int k = 1; k < 16; k <<= 1) m = fmaxf(m, __shfl_xor(m, k));
        mx[s] = m;
    }
    if (lr == 0) {
#pragma unroll
        for (int s = 0; s < 8; ++s) {
            int ag = (s >> 2) * 16 + g * 4 + (s & 3);
            redM[wid][ag] = mx[s];
        }
    }
    __syncthreads();
    float M[8];
#pragma unroll
    for (int s = 0; s < 8; ++s) {
        int ag = (s >> 2) * 16 + g * 4 + (s & 3);
        M[s] = fmaxf(fmaxf(redM[0][ag], redM[1][ag]), fmaxf(redM[2][ag], redM[3][ag]));
    }

    float le[8] = {0.f, 0.f, 0.f, 0.f, 0.f, 0.f, 0.f, 0.f};
    f32x4 pv[2][4] = {};
    unsigned char* Pw = &Psm[wid][0];
    const size_t vbase = ((size_t)b * 512 + h * 64) * 16384;
#pragma unroll
    for (int it2 = 0; it2 < 2; ++it2) {
#pragma unroll
        for (int half = 0; half < 2; ++half) {
            int it = it2 * 2 + half;
            int tk = half * 16 + lr;
#pragma unroll
            for (int s = 0; s < 8; ++s) {
                float p = __expf(sc[it][s >> 2][s & 3] - M[s]);
                le[s] += p;
                int ag = (s >> 2) * 16 + g * 4 + (s & 3);
                *(unsigned short*)(Pw + ag * 64 + ((2 * tk) ^ (((ag >> 2) & 3) << 4))) = f2bf(p);
            }
        }
        int n0w = tok0 + it2 * 32;
        bf16x8 pa[2];
#pragma unroll
        for (int mf = 0; mf < 2; ++mf) {
            int ag = mf * 16 + lr;
            pa[mf] = *(const bf16x8*)(Pw + ag * 64 + ((g * 16) ^ (((ag >> 2) & 3) << 4)));
        }
#pragma unroll
        for (int nf = 0; nf < 4; ++nf) {
            int dd = nf * 16 + lr;
            bf16x8 bv = *(const bf16x8*)(Vt + vbase + (size_t)dd * 16384 + n0w + g * 8);
#pragma unroll
            for (int mf = 0; mf < 2; ++mf)
                pv[mf][nf] = MFMA16(pa[mf], bv, pv[mf][nf]);
        }
    }

#pragma unroll
    for (int s = 0; s < 8; ++s) {
#pragma unroll
        for (int k = 1; k < 16; k <<= 1) le[s] += __shfl_xor(le[s], k);
    }
    if (lr == 0) {
#pragma unroll
        for (int s = 0; s < 8; ++s) {
            int ag = (s >> 2) * 16 + g * 4 + (s & 3);
            redL[wid][ag] = le[s];
        }
    }

#pragma unroll
    for (int mf = 0; mf < 2; ++mf)
#pragma unroll
        for (int nf = 0; nf < 4; ++nf)
#pragma unroll
            for (int r = 0; r < 4; ++r) {
                int ag = mf * 16 + g * 4 + r;
                int dd = nf * 16 + lr;
                avs[wid][ag * 64 + dd] = pv[mf][nf][r];
            }
    __syncthreads();

    float* pout = part_pv + ((size_t)bh * 64 + c) * 2048;
#pragma unroll
    for (int j = 0; j < 8; ++j) {
        int idx = tid + 256 * j;
        pout[idx] = avs[0][idx] + avs[1][idx] + avs[2][idx] + avs[3][idx];
    }
    if (wid == 0 && lr == 0) {
#pragma unroll
        for (int s = 0; s < 8; ++s) {
            int ag = (s >> 2) * 16 + g * 4 + (s & 3);
            float L = redL[0][ag] + redL[1][ag] + redL[2][ag] + redL[3][ag];
            size_t o = ((size_t)bh * 64 + c) * 64 + ag * 2;
            part_ml[o] = M[s];
            part_ml[o + 1] = L;
        }
    }
}

// ------------------------------- k_agent_comb --------------------------------
__global__ __launch_bounds__(256) void k_agent_comb(const float* __restrict__ part_pv,
                                                    const float* __restrict__ part_ml,
                                                    unsigned short* __restrict__ avbf) {
    __shared__ float scl[64][4];
    __shared__ float iLg[4], Mg[4];
    const int tid = threadIdx.x;
    const int ag0 = blockIdx.x * 4, bh = blockIdx.y;
    if (tid < 4) {
        int ag = ag0 + tid;
        const float* ml = part_ml + (size_t)bh * 4096 + ag * 2;
        float M = -3.0e38f;
#pragma unroll 4
        for (int c = 0; c < 64; ++c) M = fmaxf(M, ml[c * 64]);
        float L = 0.f;
#pragma unroll 4
        for (int c = 0; c < 64; ++c) L += __expf(ml[c * 64] - M) * ml[c * 64 + 1];
        Mg[tid] = M; iLg[tid] = 1.0f / L;
    }
    __syncthreads();
    {
        int c = tid >> 2, agl = tid & 3;
        scl[c][agl] = __expf(part_ml[(size_t)bh * 4096 + (size_t)c * 64 + (ag0 + agl) * 2] - Mg[agl]);
    }
    __syncthreads();
    const int agl = tid >> 6, dd = tid & 63;
    const float* pv = part_pv + (size_t)bh * 64 * 2048 + (size_t)(ag0 + agl) * 64 + dd;
    float acc = 0.f;
#pragma unroll 4
    for (int c = 0; c < 64; ++c) acc += scl[c][agl] * pv[(size_t)c * 2048];
    avbf[(size_t)bh * 2048 + (size_t)(ag0 + agl) * 64 + dd] = f2bf(acc * iLg[agl]);
}

// ------------------------------- k_avp ----------------------------------------
__global__ __launch_bounds__(64) void k_avp(const unsigned short* __restrict__ avbf,
                                            const unsigned short* __restrict__ Wpt,
                                            unsigned char* __restrict__ AVPt) {
    const int l = threadIdx.x & 63;
    const int bh = blockIdx.x, b = bh >> 3, h = bh & 7;
    const int g = l >> 4, lr = l & 15;
    bf16x8 avf[2][2];
#pragma unroll
    for (int mf = 0; mf < 2; ++mf)
#pragma unroll
        for (int ks = 0; ks < 2; ++ks)
            avf[mf][ks] = *(const bf16x8*)(avbf + (size_t)bh * 2048 + (mf * 16 + lr) * 64 + ks * 32 + g * 8);
    const int kst = h >> 1;
#pragma unroll 4
    for (int nf = 0; nf < 32; ++nf) {
        int j = nf * 16 + lr;
        bf16x8 w0 = *(const bf16x8*)(Wpt + (size_t)j * 512 + h * 64 + g * 8);
        bf16x8 w1 = *(const bf16x8*)(Wpt + (size_t)j * 512 + h * 64 + 32 + g * 8);
        int jt = j >> 7, row = j & 127;
#pragma unroll
        for (int mf = 0; mf < 2; ++mf) {
            f32x4 z = {0.f, 0.f, 0.f, 0.f};
            f32x4 acc = MFMA16(avf[mf][0], w0, z);
            acc = MFMA16(avf[mf][1], w1, acc);
            u16x4 o;
            o[0] = f2bf(acc[0]); o[1] = f2bf(acc[1]); o[2] = f2bf(acc[2]); o[3] = f2bf(acc[3]);
            int c8 = (h & 1) * 4 + mf * 2 + (g >> 1);
            size_t byte = ((size_t)((b * 4 + jt) * 4 + kst)) * 16384 + row * 128 +
                          ((c8 ^ (row & 7)) << 4) + (g & 1) * 8;
            *(u16x4*)(AVPt + byte) = o;
        }
    }
}

// ------------------------------- k_qattn ---------------------------------------
// MFMA q->agent softmax; reads Qbf row-major, writes Qattn TILED. grid 1024.
__global__ __launch_bounds__(256) void k_qattn(const unsigned short* __restrict__ Qbf,
                                               const unsigned short* __restrict__ abf,
                                               unsigned char* __restrict__ Qat) {
    const int tid = threadIdx.x, l = tid & 63, wid = tid >> 6;
    const int g = l >> 4, lr = l & 15;
    const int tok0 = blockIdx.x * 64;
#pragma unroll
    for (int hh = 0; hh < 2; ++hh) {
        const int h = wid * 2 + hh;
        bf16x8 af[2][2];
#pragma unroll
        for (int mf = 0; mf < 2; ++mf)
#pragma unroll
            for (int ks = 0; ks < 2; ++ks)
                af[mf][ks] = *(const bf16x8*)(abf + (size_t)h * 2048 + (mf * 16 + lr) * 64 + ks * 32 + g * 8);
        f32x4 acc[2][4] = {};
#pragma unroll
        for (int nf = 0; nf < 4; ++nf) {
            int tokn = tok0 + nf * 16 + lr;
            const unsigned short* qp = Qbf + (size_t)tokn * 512 + h * 64;
            bf16x8 q0 = *(const bf16x8*)(qp + g * 8);
            bf16x8 q1 = *(const bf16x8*)(qp + 32 + g * 8);
#pragma unroll
            for (int mf = 0; mf < 2; ++mf) {
                acc[mf][nf] = MFMA16(af[mf][0], q0, acc[mf][nf]);
                acc[mf][nf] = MFMA16(af[mf][1], q1, acc[mf][nf]);
            }
        }
        const int kst = h >> 1;
#pragma unroll
        for (int nf = 0; nf < 4; ++nf) {
            float mt = -3.0e38f;
#pragma unroll
            for (int s = 0; s < 8; ++s) mt = fmaxf(mt, acc[s >> 2][nf][s & 3] * 0.125f);
            mt = fmaxf(mt, __shfl_xor(mt, 16));
            mt = fmaxf(mt, __shfl_xor(mt, 32));
            float e[8], sum = 0.f;
#pragma unroll
            for (int s = 0; s < 8; ++s) {
                e[s] = __expf(acc[s >> 2][nf][s & 3] * 0.125f - mt);
                sum += e[s];
            }
            sum += __shfl_xor(sum, 16);
            sum += __shfl_xor(sum, 32);
            float inv = 1.0f / sum;
            int tokn = tok0 + nf * 16 + lr;
            int mtile = tokn >> 7, row = tokn & 127;
#pragma unroll
            for (int mf = 0; mf < 2; ++mf) {
                u16x4 o;
#pragma unroll
                for (int r = 0; r < 4; ++r) o[r] = f2bf(e[mf * 4 + r] * inv);
                int c8 = (h & 1) * 4 + mf * 2 + (g >> 1);
                size_t byte = ((size_t)(mtile * 4 + kst)) * 16384 + row * 128 +
                              ((c8 ^ (row & 7)) << 4) + (g & 1) * 8;
                *(u16x4*)(Qat + byte) = o;
            }
        }
    }
}

// ------------------------------- k_out -----------------------------------------
// BM=128, BN=128, BK=64, K=256; gload_lds staging of tiled Qattn/AVPt.
__global__ __launch_bounds__(256) void k_out(const unsigned char* __restrict__ Qat,
                                             const unsigned char* __restrict__ AVPt,
                                             const int* __restrict__ mask,
                                             float* __restrict__ out) {
    __shared__ __align__(16) unsigned char As[16384];
    __shared__ __align__(16) unsigned char Bs[16384];
    const int tid = threadIdx.x, l = tid & 63, wid = tid >> 6;
    const int wm = wid >> 1, wn = wid & 1;
    const int g = l >> 4, lr = l & 15;
    const int d = blockIdx.x;
    const int nt = (d >> 3) & 3;
    const int mt = (d & 7) + ((d >> 5) << 3);
    const int m0 = mt * 128, j0 = nt * 128;
    const int b = m0 >> 14;
    f32x4 acc[4][4] = {};

    for (int ks = 0; ks < 4; ++ks) {
        const size_t abase = ((size_t)(mt * 4 + ks)) * 16384;
        const size_t bbase = ((size_t)((b * 4 + nt) * 4 + ks)) * 16384;
#pragma unroll
        for (int i = 0; i < 4; ++i) {
            gl2lds16(Qat + abase + i * 4096 + tid * 16, As + i * 4096 + tid * 16);
            gl2lds16(AVPt + bbase + i * 4096 + tid * 16, Bs + i * 4096 + tid * 16);
        }
        __syncthreads();
        bf16x8 af[4][2];
#pragma unroll
        for (int mf = 0; mf < 4; ++mf) {
            int row = wm * 64 + mf * 16 + lr;
#pragma unroll
            for (int k2 = 0; k2 < 2; ++k2)
                af[mf][k2] = *(const bf16x8*)(As + row * 128 + (((k2 * 4 + g) ^ (row & 7)) << 4));
        }
#pragma unroll
        for (int k2 = 0; k2 < 2; ++k2) {
#pragma unroll
            for (int nf = 0; nf < 4; ++nf) {
                int brow = wn * 64 + nf * 16 + lr;
                bf16x8 bv = *(const bf16x8*)(Bs + brow * 128 + (((k2 * 4 + g) ^ (brow & 7)) << 4));
#pragma unroll
                for (int mf = 0; mf < 4; ++mf)
                    acc[mf][nf] = MFMA16(af[mf][k2], bv, acc[mf][nf]);
            }
        }
        __syncthreads();
    }
#pragma unroll
    for (int mf = 0; mf < 4; ++mf) {
        int trow = m0 + wm * 64 + mf * 16 + g * 4;
#pragma unroll
        for (int r = 0; r < 4; ++r) {
            float mv = (mask[trow + r] > 0) ? 1.0f : 0.0f;
#pragma unroll
            for (int nf = 0; nf < 4; ++nf) {
                int j = j0 + wn * 64 + nf * 16 + lr;
                out[(size_t)(trow + r) * 512 + j] = acc[mf][nf][r] * mv;
            }
        }
    }
}

// ------------------------------- launch -----------------------------------------
extern "C" void kernel_launch(void* const* d_in, const int* in_sizes, int n_in,
                              void* d_out, int out_size, void* d_ws, size_t ws_size,
                              hipStream_t stream) {
    const float* x  = (const float*)d_in[0];
    const int*  mk  = (const int*)d_in[1];
    const float* at = (const float*)d_in[2];
    const float* Wq = (const float*)d_in[3];
    const float* Wk = (const float*)d_in[4];
    const float* Wv = (const float*)d_in[5];
    const float* Wp = (const float*)d_in[6];
    float* out = (float*)d_out;
    char* ws = (char*)d_ws;

    unsigned char*  Qat   = (unsigned char*)(ws);                        // [0,32) tiled q-attn weights
    float* part_pv = (float*)(ws + ((size_t)32 << 20));                  // [32,48.8)
    float* part_ml = (float*)(ws + ((size_t)52 << 20));                  // [52,52.5)
    unsigned short* Kbf   = (unsigned short*)(ws + ((size_t)64 << 20));  // [64,128)
    unsigned short* Vt    = (unsigned short*)(ws + ((size_t)128 << 20)); // [128,192)
    unsigned short* Qbf   = (unsigned short*)(ws + ((size_t)192 << 20)); // [192,256)
    unsigned short* Wpt   = (unsigned short*)(ws + ((size_t)256 << 20)); // [256,256.5)
    unsigned char*  wtl   = (unsigned char*)(ws + ((size_t)258 << 20));  // [258,259.5)
    unsigned short* abf   = (unsigned short*)(ws + ((size_t)259 << 20) + (512 << 10)); // 259.5 MiB
    unsigned short* avbf  = (unsigned short*)(ws + ((size_t)259 << 20) + (576 << 10)); // +64 KiB
    unsigned char*  AVPt  = (unsigned char*)(ws + ((size_t)260 << 20));  // [260,261)

    k_w_t_p<<<dim3(16, 16), 256, 0, stream>>>(Wp, Wpt);
    k_w_tile<<<dim3(8, 8, 3), 256, 0, stream>>>(Wq, Wk, Wv, wtl);
    k_pack_a<<<64, 256, 0, stream>>>(at, abf);
    k_qkv<<<4096, 512, 0, stream>>>(x, wtl, Qbf, Kbf, Vt);
    k_agent_part<<<dim3(64, 32), 256, 0, stream>>>(Kbf, Vt, abf, mk, part_pv, part_ml);
    k_agent_comb<<<dim3(8, 32), 256, 0, stream>>>(part_pv, part_ml, avbf);
    k_avp<<<32, 64, 0, stream>>>(avbf, Wpt, AVPt);
    k_qattn<<<1024, 256, 0, stream>>>(Qbf, abf, Qat);
    k_out<<<2048, 256, 0, stream>>>(Qat, AVPt, mk, out);
}

// Round 8
// 266.172 us; speedup vs baseline: 1.2729x; 1.2729x over previous
//
#include <hip/hip_runtime.h>

// ---------------------------------------------------------------------------
// MaskedSuperAttention (agent attention), B=4 N=16384 C=512 H=8 HD=64 NA=32
// R8 restructure: score = x·(Wk@a^T)  =>  K never materialized.
//   k_cvt_x      : x f32 -> xt bf16 TILED (128x64 swizzled tiles)
//   k_w_t_p      : Wproj -> Wpt bf16 [n][k] (for k_avp)
//   k_w_tile     : Wq,Wv -> wtl2 tiled-swizzled (B operand, gload_lds)
//   k_akw        : akw[c][h*32+ag] = sum_d a[ag][h64+d]*Wk[c][h64+d] -> wtl2 S
//   k_pack_a     : agents -> abf (for k_qattn)
//   k_qkvs       : GEMM x@[Wq|Wv|akw] (BN=160, R4 loop structure) ; epilogue:
//                  Q->HBM, V->LDS, scores: mask+block-M/L, P->LDS, P@V MFMA,
//                  cross-wave reduce -> flash partials (M,L,PV) per 128-tok
//                  chunk per (b,h). K,V never touch HBM.
//   k_agent_comb : merge 128 partials per (b,h) -> agent_v bf16
//   k_avp        : AVP = agent_v @ Wproj -> AVPt TILED
//   k_qattn      : MFMA softmax(q.a*scale) -> Qattn TILED
//   k_out        : out = (Qattn @ AVPt) * keymask
// Tiled layout: tile 128x64 (16KiB); byte(row,c8)= row*128 + ((c8^(row&7))<<4)
// ---------------------------------------------------------------------------

typedef float  f32x4   __attribute__((ext_vector_type(4)));
typedef short  bf16x8  __attribute__((ext_vector_type(8)));
typedef unsigned short u16x4 __attribute__((ext_vector_type(4)));
typedef unsigned short u16x8 __attribute__((ext_vector_type(8)));

#define MFMA16(a, b, c) __builtin_amdgcn_mfma_f32_16x16x32_bf16((a), (b), (c), 0, 0, 0)

__device__ __forceinline__ unsigned short f2bf(float f) {
    unsigned u = __builtin_bit_cast(unsigned, f);
    u += 0x7FFFu + ((u >> 16) & 1u);        // RTNE
    return (unsigned short)(u >> 16);
}
__device__ __forceinline__ void gl2lds16(const void* g, void* l) {
    __builtin_amdgcn_global_load_lds(
        (const __attribute__((address_space(1))) unsigned int*)g,
        (__attribute__((address_space(3))) unsigned int*)l, 16, 0, 0);
}

// ------------------------------- k_cvt_x -----------------------------------
__global__ __launch_bounds__(256) void k_cvt_x(const float* __restrict__ x,
                                               unsigned char* __restrict__ xt) {
    int v = blockIdx.x * 256 + threadIdx.x;
    int tile = v >> 10;
    int q = v & 1023;
    int row = q >> 3, c = q & 7;
    int mt = tile >> 3, ks = tile & 7;
    const float* sp = x + ((size_t)(mt * 128 + row)) * 512 + ks * 64 + c * 8;
    float4 v0 = *(const float4*)sp;
    float4 v1 = *(const float4*)(sp + 4);
    u16x8 o;
    o[0] = f2bf(v0.x); o[1] = f2bf(v0.y); o[2] = f2bf(v0.z); o[3] = f2bf(v0.w);
    o[4] = f2bf(v1.x); o[5] = f2bf(v1.y); o[6] = f2bf(v1.z); o[7] = f2bf(v1.w);
    *(u16x8*)(xt + (size_t)tile * 16384 + row * 128 + ((c ^ (row & 7)) << 4)) = o;
}

// ------------------------------- k_w_t_p ------------------------------------
__global__ __launch_bounds__(256) void k_w_t_p(const float* __restrict__ Wp,
                                               unsigned short* __restrict__ Wpt) {
    __shared__ float t[32][33];
    const int k0 = blockIdx.y * 32, n0 = blockIdx.x * 32;
#pragma unroll
    for (int j = 0; j < 4; ++j) {
        int i = threadIdx.x + 256 * j;
        int ky = i >> 5, nx = i & 31;
        t[ky][nx] = Wp[(size_t)(k0 + ky) * 512 + n0 + nx];
    }
    __syncthreads();
#pragma unroll
    for (int j = 0; j < 4; ++j) {
        int i = threadIdx.x + 256 * j;
        int ny = i >> 5, kx = i & 31;
        Wpt[(size_t)(n0 + ny) * 512 + k0 + kx] = f2bf(t[kx][ny]);
    }
}

// ------------------------------- k_w_tile -----------------------------------
// Wq,Wv -> wtl2 tile group (nt,ks): [0,8K) Q, [8K,16K) V, ([16K,20K) S by k_akw)
__global__ __launch_bounds__(256) void k_w_tile(const float* __restrict__ Wq,
                                                const float* __restrict__ Wv,
                                                unsigned char* __restrict__ wtl2) {
    const int ks = blockIdx.x, nt = blockIdx.y, mat = blockIdx.z;
    const float* src = (mat == 0) ? Wq : Wv;
    unsigned char* dst = wtl2 + ((size_t)(nt * 8 + ks)) * 20480 + mat * 8192;
    const int row = threadIdx.x & 63;
#pragma unroll
    for (int cc = 0; cc < 2; ++cc) {
        int c = (threadIdx.x >> 6) + cc * 4;
        u16x8 o;
#pragma unroll
        for (int j = 0; j < 8; ++j)
            o[j] = f2bf(src[(size_t)(ks * 64 + c * 8 + j) * 512 + nt * 64 + row]);
        *(u16x8*)(dst + row * 128 + ((c ^ (row & 7)) << 4)) = o;
    }
}

// ------------------------------- k_akw --------------------------------------
// akw tile for (h,ks): S[ag][kk] = sum_d at[ag][h*64+d] * Wk[ks*64+kk][h*64+d]
// grid (8 ks, 8 h), block 256 (row=tid>>3 ag, c8=tid&7)
__global__ __launch_bounds__(256) void k_akw(const float* __restrict__ at,
                                             const float* __restrict__ Wk,
                                             unsigned char* __restrict__ wtl2) {
    const int ks = blockIdx.x, h = blockIdx.y;
    const int row = threadIdx.x >> 3, c8 = threadIdx.x & 7;
    const float* ar = at + row * 512 + h * 64;
    float accv[8];
#pragma unroll
    for (int j = 0; j < 8; ++j) {
        const float* wr = Wk + (size_t)(ks * 64 + c8 * 8 + j) * 512 + h * 64;
        float s = 0.f;
#pragma unroll 8
        for (int d = 0; d < 64; ++d) s += ar[d] * wr[d];
        accv[j] = s;
    }
    u16x8 o;
#pragma unroll
    for (int j = 0; j < 8; ++j) o[j] = f2bf(accv[j]);
    *(u16x8*)(wtl2 + ((size_t)(h * 8 + ks)) * 20480 + 16384 +
              row * 128 + ((c8 ^ (row & 7)) << 4)) = o;
}

// ------------------------------- k_pack_a -----------------------------------
__global__ __launch_bounds__(256) void k_pack_a(const float* __restrict__ at,
                                                unsigned short* __restrict__ abf) {
    int idx = threadIdx.x + blockIdx.x * 256;
    int h = idx >> 11, ag = (idx >> 6) & 31, d = idx & 63;
    abf[idx] = f2bf(at[ag * 512 + h * 64 + d]);
}

// ------------------------------- k_qkvs --------------------------------------
// BM=128, BN=160 (Q64,V64,S32), BK=64. 4 waves, each 32 tok x all 160 cols.
// Main loop = R4 structure (gl2lds A 16KB + B 20KB, 2 barriers/step).
// grid 4096 (XCD-swizzled), block 256. LDS 41984 B (epilogue overlays).
__global__ __launch_bounds__(256) void k_qkvs(const unsigned char* __restrict__ xt,
                                              const unsigned char* __restrict__ wtl2,
                                              const int* __restrict__ mask,
                                              unsigned short* __restrict__ Qbf,
                                              float* __restrict__ part_pv,
                                              float* __restrict__ part_ml) {
    __shared__ __align__(16) unsigned char S_[41984];
    unsigned char* As = S_;                 // [0,16K) main
    unsigned char* Bs = S_ + 16384;         // [16K,36.8K) main
    const int tid = threadIdx.x, l = tid & 63, wid = tid >> 6;
    const int g = l >> 4, lr = l & 15;
    const int dd = blockIdx.x;
    const int nt = (dd >> 3) & 7;
    const int mt = (dd & 7) + ((dd >> 6) << 3);
    const int m0 = mt * 128, n0 = nt * 64;
    const int b = mt >> 7, chunk = mt & 127, bh = b * 8 + nt;

    f32x4 acc[2][10] = {};

    for (int ks = 0; ks < 8; ++ks) {
        const size_t abase = ((size_t)(mt * 8 + ks)) * 16384;
        const size_t bbase = ((size_t)(nt * 8 + ks)) * 20480;
#pragma unroll
        for (int i = 0; i < 4; ++i)
            gl2lds16(xt + abase + i * 4096 + tid * 16, As + i * 4096 + tid * 16);
#pragma unroll
        for (int i = 0; i < 5; ++i)
            gl2lds16(wtl2 + bbase + i * 4096 + tid * 16, Bs + i * 4096 + tid * 16);
        __syncthreads();

        bf16x8 af[2][2];
#pragma unroll
        for (int mf = 0; mf < 2; ++mf) {
            int row = wid * 32 + mf * 16 + lr;
#pragma unroll
            for (int k2 = 0; k2 < 2; ++k2)
                af[mf][k2] = *(const bf16x8*)(As + row * 128 + (((k2 * 4 + g) ^ (row & 7)) << 4));
        }
#pragma unroll
        for (int k2 = 0; k2 < 2; ++k2) {
#pragma unroll
            for (int nf = 0; nf < 10; ++nf) {
                const int reg = (nf < 4) ? 0 : ((nf < 8) ? 8192 : 16384);
                const int sub = (nf < 4) ? nf : ((nf < 8) ? nf - 4 : nf - 8);
                int brow = sub * 16 + lr;
                bf16x8 bv = *(const bf16x8*)(Bs + reg + brow * 128 +
                                             (((k2 * 4 + g) ^ (brow & 7)) << 4));
#pragma unroll
                for (int mf = 0; mf < 2; ++mf)
                    acc[mf][nf] = MFMA16(af[mf][k2], bv, acc[mf][nf]);
            }
        }
        __syncthreads();
    }

    // ---------------- epilogue ----------------
    unsigned char* Psm_w = S_ + wid * 2048;          // [0,8K)   (over As, dead)
    unsigned char* Ev_w  = S_ + 8192 + wid * 4096;   // [8K,24K) (over As/Bs)
    float* avsH = (float*)(S_ + 24576);              // [24K,40K)
    float* redM = (float*)(S_ + 40960);              // [40K,+512) [4][32]
    float* redL = (float*)(S_ + 41472);              // +512

    // Q -> HBM (row-major, as R4)
#pragma unroll
    for (int mf = 0; mf < 2; ++mf) {
        int trow = wid * 32 + mf * 16 + g * 4;
#pragma unroll
        for (int sub = 0; sub < 4; ++sub) {
            int dc = n0 + sub * 16 + lr;
#pragma unroll
            for (int r = 0; r < 4; ++r)
                Qbf[(size_t)(m0 + trow + r) * 512 + dc] = f2bf(acc[mf][sub][r]);
        }
    }

    // V -> Ev (per-wave [64 d][32 tok], u16x4 vector writes, bank-swizzled)
#pragma unroll
    for (int mf = 0; mf < 2; ++mf)
#pragma unroll
        for (int vf = 0; vf < 4; ++vf) {
            int d5 = vf * 16 + lr;
            u16x4 vv;
            vv[0] = f2bf(acc[mf][4 + vf][0]); vv[1] = f2bf(acc[mf][4 + vf][1]);
            vv[2] = f2bf(acc[mf][4 + vf][2]); vv[3] = f2bf(acc[mf][4 + vf][3]);
            *(u16x4*)(Ev_w + d5 * 64 + ((mf * 32 + g * 8) ^ ((d5 & 3) << 4))) = vv;
        }

    // scores: scale + mask
    float sc2[2][2][4];
#pragma unroll
    for (int mf = 0; mf < 2; ++mf) {
        int4 mv = *(const int4*)(mask + m0 + wid * 32 + mf * 16 + g * 4);
        int mvr[4] = {mv.x, mv.y, mv.z, mv.w};
#pragma unroll
        for (int sf = 0; sf < 2; ++sf)
#pragma unroll
            for (int r = 0; r < 4; ++r)
                sc2[mf][sf][r] = (mvr[r] > 0) ? acc[mf][8 + sf][r] * 0.125f : -1.0e9f;
    }
    // wave max per agent, then block max via LDS
    float mw[2];
#pragma unroll
    for (int sf = 0; sf < 2; ++sf) {
        float m = sc2[0][sf][0];
#pragma unroll
        for (int mf = 0; mf < 2; ++mf)
#pragma unroll
            for (int r = 0; r < 4; ++r) m = fmaxf(m, sc2[mf][sf][r]);
        m = fmaxf(m, __shfl_xor(m, 16));
        m = fmaxf(m, __shfl_xor(m, 32));
        mw[sf] = m;
    }
    if (g == 0) { redM[wid * 32 + lr] = mw[0]; redM[wid * 32 + 16 + lr] = mw[1]; }
    __syncthreads();
    float Mb[2];
#pragma unroll
    for (int sf = 0; sf < 2; ++sf) {
        int ag = sf * 16 + lr;
        Mb[sf] = fmaxf(fmaxf(redM[ag], redM[32 + ag]), fmaxf(redM[64 + ag], redM[96 + ag]));
    }
    // P = exp(s-Mb) -> Psm (agent_part's proven layout); L partial
    float le[2] = {0.f, 0.f};
#pragma unroll
    for (int mf = 0; mf < 2; ++mf)
#pragma unroll
        for (int sf = 0; sf < 2; ++sf)
#pragma unroll
            for (int r = 0; r < 4; ++r) {
                float p = __expf(sc2[mf][sf][r] - Mb[sf]);
                le[sf] += p;
                int ag = sf * 16 + lr;
                int tk = mf * 16 + g * 4 + r;
                *(unsigned short*)(Psm_w + ag * 64 + ((2 * tk) ^ (((ag >> 2) & 3) << 4))) = f2bf(p);
            }
#pragma unroll
    for (int sf = 0; sf < 2; ++sf) {
        le[sf] += __shfl_xor(le[sf], 16);
        le[sf] += __shfl_xor(le[sf], 32);
    }
    if (g == 0) { redL[wid * 32 + lr] = le[0]; redL[wid * 32 + 16 + lr] = le[1]; }

    // P @ V (one K=32 MFMA step; within-wave LDS, in-order)
    bf16x8 pa[2];
#pragma unroll
    for (int agf = 0; agf < 2; ++agf) {
        int ag = agf * 16 + lr;
        pa[agf] = *(const bf16x8*)(Psm_w + ag * 64 + ((g * 16) ^ (((ag >> 2) & 3) << 4)));
    }
    f32x4 pv[2][4] = {};
#pragma unroll
    for (int vf = 0; vf < 4; ++vf) {
        int d5 = vf * 16 + lr;
        bf16x8 bv = *(const bf16x8*)(Ev_w + d5 * 64 + ((g * 16) ^ ((d5 & 3) << 4)));
#pragma unroll
        for (int agf = 0; agf < 2; ++agf)
            pv[agf][vf] = MFMA16(pa[agf], bv, pv[agf][vf]);
    }

    // cross-wave PV reduce (two 16-agent halves to fit 16KB avsH)
    float* pout = part_pv + ((size_t)bh * 128 + chunk) * 2048;
#pragma unroll
    for (int agf = 0; agf < 2; ++agf) {
#pragma unroll
        for (int vf = 0; vf < 4; ++vf)
#pragma unroll
            for (int r = 0; r < 4; ++r)
                avsH[wid * 1024 + (g * 4 + r) * 64 + vf * 16 + lr] = pv[agf][vf][r];
        __syncthreads();
#pragma unroll
        for (int j = 0; j < 4; ++j) {
            int idx = tid + 256 * j;
            pout[agf * 1024 + idx] = avsH[idx] + avsH[1024 + idx] +
                                     avsH[2048 + idx] + avsH[3072 + idx];
        }
        if (agf == 0) __syncthreads();
    }
    // M,L partials
    if (wid == 0 && g == 0) {
        size_t o = ((size_t)bh * 128 + chunk) * 64;
        float L0 = redL[lr] + redL[32 + lr] + redL[64 + lr] + redL[96 + lr];
        float L1 = redL[16 + lr] + redL[48 + lr] + redL[80 + lr] + redL[112 + lr];
        part_ml[o + lr * 2] = Mb[0];
        part_ml[o + lr * 2 + 1] = L0;
        part_ml[o + (16 + lr) * 2] = Mb[1];
        part_ml[o + (16 + lr) * 2 + 1] = L1;
    }
}

// ------------------------------- k_agent_comb --------------------------------
// merge 128 chunks per (b,h). grid (8 agent-groups, 32 bh), block 256.
__global__ __launch_bounds__(256) void k_agent_comb(const float* __restrict__ part_pv,
                                                    const float* __restrict__ part_ml,
                                                    unsigned short* __restrict__ avbf) {
    __shared__ float scl[128][4];
    __shared__ float iLg[4], Mg[4];
    const int tid = threadIdx.x;
    const int ag0 = blockIdx.x * 4, bh = blockIdx.y;
    if (tid < 4) {
        int ag = ag0 + tid;
        const float* ml = part_ml + (size_t)bh * 8192 + ag * 2;
        float M = -3.0e38f;
#pragma unroll 4
        for (int c = 0; c < 128; ++c) M = fmaxf(M, ml[c * 64]);
        float L = 0.f;
#pragma unroll 4
        for (int c = 0; c < 128; ++c) L += __expf(ml[c * 64] - M) * ml[c * 64 + 1];
        Mg[tid] = M; iLg[tid] = 1.0f / L;
    }
    __syncthreads();
#pragma unroll
    for (int it = 0; it < 2; ++it) {
        int idx = tid + 256 * it;
        int c = idx >> 2, agl = idx & 3;
        scl[c][agl] = __expf(part_ml[(size_t)bh * 8192 + (size_t)c * 64 + (ag0 + agl) * 2] - Mg[agl]);
    }
    __syncthreads();
    const int agl = tid >> 6, d5 = tid & 63;
    const float* pv = part_pv + (size_t)bh * 128 * 2048 + (size_t)(ag0 + agl) * 64 + d5;
    float a = 0.f;
#pragma unroll 4
    for (int c = 0; c < 128; ++c) a += scl[c][agl] * pv[(size_t)c * 2048];
    avbf[(size_t)bh * 2048 + (size_t)(ag0 + agl) * 64 + d5] = f2bf(a * iLg[agl]);
}

// ------------------------------- k_avp ----------------------------------------
__global__ __launch_bounds__(64) void k_avp(const unsigned short* __restrict__ avbf,
                                            const unsigned short* __restrict__ Wpt,
                                            unsigned char* __restrict__ AVPt) {
    const int l = threadIdx.x & 63;
    const int bh = blockIdx.x, b = bh >> 3, h = bh & 7;
    const int g = l >> 4, lr = l & 15;
    bf16x8 avf[2][2];
#pragma unroll
    for (int mf = 0; mf < 2; ++mf)
#pragma unroll
        for (int ks = 0; ks < 2; ++ks)
            avf[mf][ks] = *(const bf16x8*)(avbf + (size_t)bh * 2048 + (mf * 16 + lr) * 64 + ks * 32 + g * 8);
    const int kst = h >> 1;
#pragma unroll 4
    for (int nf = 0; nf < 32; ++nf) {
        int j = nf * 16 + lr;
        bf16x8 w0 = *(const bf16x8*)(Wpt + (size_t)j * 512 + h * 64 + g * 8);
        bf16x8 w1 = *(const bf16x8*)(Wpt + (size_t)j * 512 + h * 64 + 32 + g * 8);
        int jt = j >> 7, row = j & 127;
#pragma unroll
        for (int mf = 0; mf < 2; ++mf) {
            f32x4 z = {0.f, 0.f, 0.f, 0.f};
            f32x4 acc = MFMA16(avf[mf][0], w0, z);
            acc = MFMA16(avf[mf][1], w1, acc);
            u16x4 o;
            o[0] = f2bf(acc[0]); o[1] = f2bf(acc[1]); o[2] = f2bf(acc[2]); o[3] = f2bf(acc[3]);
            int c8 = (h & 1) * 4 + mf * 2 + (g >> 1);
            size_t byte = ((size_t)((b * 4 + jt) * 4 + kst)) * 16384 + row * 128 +
                          ((c8 ^ (row & 7)) << 4) + (g & 1) * 8;
            *(u16x4*)(AVPt + byte) = o;
        }
    }
}

// ------------------------------- k_qattn ---------------------------------------
__global__ __launch_bounds__(256) void k_qattn(const unsigned short* __restrict__ Qbf,
                                               const unsigned short* __restrict__ abf,
                                               unsigned char* __restrict__ Qat) {
    const int tid = threadIdx.x, l = tid & 63, wid = tid >> 6;
    const int g = l >> 4, lr = l & 15;
    const int tok0 = blockIdx.x * 64;
#pragma unroll
    for (int hh = 0; hh < 2; ++hh) {
        const int h = wid * 2 + hh;
        bf16x8 af[2][2];
#pragma unroll
        for (int mf = 0; mf < 2; ++mf)
#pragma unroll
            for (int ks = 0; ks < 2; ++ks)
                af[mf][ks] = *(const bf16x8*)(abf + (size_t)h * 2048 + (mf * 16 + lr) * 64 + ks * 32 + g * 8);
        f32x4 acc[2][4] = {};
#pragma unroll
        for (int nf = 0; nf < 4; ++nf) {
            int tokn = tok0 + nf * 16 + lr;
            const unsigned short* qp = Qbf + (size_t)tokn * 512 + h * 64;
            bf16x8 q0 = *(const bf16x8*)(qp + g * 8);
            bf16x8 q1 = *(const bf16x8*)(qp + 32 + g * 8);
#pragma unroll
            for (int mf = 0; mf < 2; ++mf) {
                acc[mf][nf] = MFMA16(af[mf][0], q0, acc[mf][nf]);
                acc[mf][nf] = MFMA16(af[mf][1], q1, acc[mf][nf]);
            }
        }
        const int kst = h >> 1;
#pragma unroll
        for (int nf = 0; nf < 4; ++nf) {
            float mt = -3.0e38f;
#pragma unroll
            for (int s = 0; s < 8; ++s) mt = fmaxf(mt, acc[s >> 2][nf][s & 3] * 0.125f);
            mt = fmaxf(mt, __shfl_xor(mt, 16));
            mt = fmaxf(mt, __shfl_xor(mt, 32));
            float e[8], sum = 0.f;
#pragma unroll
            for (int s = 0; s < 8; ++s) {
                e[s] = __expf(acc[s >> 2][nf][s & 3] * 0.125f - mt);
                sum += e[s];
            }
            sum += __shfl_xor(sum, 16);
            sum += __shfl_xor(sum, 32);
            float inv = 1.0f / sum;
            int tokn = tok0 + nf * 16 + lr;
            int mtile = tokn >> 7, row = tokn & 127;
#pragma unroll
            for (int mf = 0; mf < 2; ++mf) {
                u16x4 o;
#pragma unroll
                for (int r = 0; r < 4; ++r) o[r] = f2bf(e[mf * 4 + r] * inv);
                int c8 = (h & 1) * 4 + mf * 2 + (g >> 1);
                size_t byte = ((size_t)(mtile * 4 + kst)) * 16384 + row * 128 +
                              ((c8 ^ (row & 7)) << 4) + (g & 1) * 8;
                *(u16x4*)(Qat + byte) = o;
            }
        }
    }
}

// ------------------------------- k_out -----------------------------------------
__global__ __launch_bounds__(256) void k_out(const unsigned char* __restrict__ Qat,
                                             const unsigned char* __restrict__ AVPt,
                                             const int* __restrict__ mask,
                                             float* __restrict__ out) {
    __shared__ __align__(16) unsigned char As[16384];
    __shared__ __align__(16) unsigned char Bs[16384];
    const int tid = threadIdx.x, l = tid & 63, wid = tid >> 6;
    const int wm = wid >> 1, wn = wid & 1;
    const int g = l >> 4, lr = l & 15;
    const int d = blockIdx.x;
    const int nt = (d >> 3) & 3;
    const int mt = (d & 7) + ((d >> 5) << 3);
    const int m0 = mt * 128, j0 = nt * 128;
    const int b = m0 >> 14;
    f32x4 acc[4][4] = {};

    for (int ks = 0; ks < 4; ++ks) {
        const size_t abase = ((size_t)(mt * 4 + ks)) * 16384;
        const size_t bbase = ((size_t)((b * 4 + nt) * 4 + ks)) * 16384;
#pragma unroll
        for (int i = 0; i < 4; ++i) {
            gl2lds16(Qat + abase + i * 4096 + tid * 16, As + i * 4096 + tid * 16);
            gl2lds16(AVPt + bbase + i * 4096 + tid * 16, Bs + i * 4096 + tid * 16);
        }
        __syncthreads();
        bf16x8 af[4][2];
#pragma unroll
        for (int mf = 0; mf < 4; ++mf) {
            int row = wm * 64 + mf * 16 + lr;
#pragma unroll
            for (int k2 = 0; k2 < 2; ++k2)
                af[mf][k2] = *(const bf16x8*)(As + row * 128 + (((k2 * 4 + g) ^ (row & 7)) << 4));
        }
#pragma unroll
        for (int k2 = 0; k2 < 2; ++k2) {
#pragma unroll
            for (int nf = 0; nf < 4; ++nf) {
                int brow = wn * 64 + nf * 16 + lr;
                bf16x8 bv = *(const bf16x8*)(Bs + brow * 128 + (((k2 * 4 + g) ^ (brow & 7)) << 4));
#pragma unroll
                for (int mf = 0; mf < 4; ++mf)
                    acc[mf][nf] = MFMA16(af[mf][k2], bv, acc[mf][nf]);
            }
        }
        __syncthreads();
    }
#pragma unroll
    for (int mf = 0; mf < 4; ++mf) {
        int trow = m0 + wm * 64 + mf * 16 + g * 4;
#pragma unroll
        for (int r = 0; r < 4; ++r) {
            float mv = (mask[trow + r] > 0) ? 1.0f : 0.0f;
#pragma unroll
            for (int nf = 0; nf < 4; ++nf) {
                int j = j0 + wn * 64 + nf * 16 + lr;
                out[(size_t)(trow + r) * 512 + j] = acc[mf][nf][r] * mv;
            }
        }
    }
}

// ------------------------------- launch -----------------------------------------
extern "C" void kernel_launch(void* const* d_in, const int* in_sizes, int n_in,
                              void* d_out, int out_size, void* d_ws, size_t ws_size,
                              hipStream_t stream) {
    const float* x  = (const float*)d_in[0];
    const int*  mk  = (const int*)d_in[1];
    const float* at = (const float*)d_in[2];
    const float* Wq = (const float*)d_in[3];
    const float* Wk = (const float*)d_in[4];
    const float* Wv = (const float*)d_in[5];
    const float* Wp = (const float*)d_in[6];
    float* out = (float*)d_out;
    char* ws = (char*)d_ws;

    unsigned char*  xt    = (unsigned char*)(ws);                        // [0,64) tiled x
    unsigned char*  Qat   = (unsigned char*)(ws);                        // [0,32) alias (after k_qkvs)
    float* part_pv = (float*)(ws + ((size_t)64 << 20));                  // [64,98) 33.5 MiB
    float* part_ml = (float*)(ws + ((size_t)100 << 20));                 // [100,101) 1 MiB
    unsigned short* Qbf   = (unsigned short*)(ws + ((size_t)192 << 20)); // [192,256)
    unsigned short* Wpt   = (unsigned short*)(ws + ((size_t)256 << 20)); // [256,256.5)
    unsigned char*  wtl2  = (unsigned char*)(ws + ((size_t)258 << 20));  // [258,259.3) 1.31 MiB
    unsigned short* abf   = (unsigned short*)(ws + ((size_t)259 << 20) + (512 << 10)); // 259.5 MiB
    unsigned short* avbf  = (unsigned short*)(ws + ((size_t)259 << 20) + (576 << 10));
    unsigned char*  AVPt  = (unsigned char*)(ws + ((size_t)260 << 20));  // [260,261)

    k_cvt_x<<<16384, 256, 0, stream>>>(x, xt);
    k_w_t_p<<<dim3(16, 16), 256, 0, stream>>>(Wp, Wpt);
    k_w_tile<<<dim3(8, 8, 2), 256, 0, stream>>>(Wq, Wv, wtl2);
    k_akw<<<dim3(8, 8), 256, 0, stream>>>(at, Wk, wtl2);
    k_pack_a<<<64, 256, 0, stream>>>(at, abf);
    k_qkvs<<<4096, 256, 0, stream>>>(xt, wtl2, mk, Qbf, part_pv, part_ml);
    k_agent_comb<<<dim3(8, 32), 256, 0, stream>>>(part_pv, part_ml, avbf);
    k_avp<<<32, 64, 0, stream>>>(avbf, Wpt, AVPt);
    k_qattn<<<1024, 256, 0, stream>>>(Qbf, abf, Qat);
    k_out<<<2048, 256, 0, stream>>>(Qat, AVPt, mk, out);
}

// Round 9
// 244.501 us; speedup vs baseline: 1.3857x; 1.0886x over previous
//
#include <hip/hip_runtime.h>

// ---------------------------------------------------------------------------
// MaskedSuperAttention (agent attention), B=4 N=16384 C=512 H=8 HD=64 NA=32
// R9: score1 = x·(Wk@a^T), score2 = x·(Wq@a^T)  =>  NEITHER K NOR Q exists.
//   k_cvt_x      : x f32 -> xt bf16 TILED (128x64 swizzled tiles)
//   k_w_t_p      : Wproj -> Wpt bf16 [n][k] (for k_avp)
//   k_w_tile     : Wv -> wtl2 tiled-swizzled (B operand V region)
//   k_akw        : Sk = Wk@a^T, Sq = Wq@a^T -> wtl2 score regions (z=2)
//   k_qkvs       : GEMM x@[Wv|akw|aqw] (BN=128) ; epilogue: V->LDS,
//                  key-score flash partial (M,L,PV), q-score softmax -> Qat.
//                  Q,K,V never touch HBM.
//   k_agent_comb : merge 128 partials per (b,h) -> agent_v bf16
//   k_avp        : AVP = agent_v @ Wproj -> AVPt TILED
//   k_out        : out = (Qattn @ AVPt) * keymask
// Tiled layout: tile 128x64 (16KiB); byte(row,c8)= row*128 + ((c8^(row&7))<<4)
// ---------------------------------------------------------------------------

typedef float  f32x4   __attribute__((ext_vector_type(4)));
typedef short  bf16x8  __attribute__((ext_vector_type(8)));
typedef unsigned short u16x4 __attribute__((ext_vector_type(4)));
typedef unsigned short u16x8 __attribute__((ext_vector_type(8)));

#define MFMA16(a, b, c) __builtin_amdgcn_mfma_f32_16x16x32_bf16((a), (b), (c), 0, 0, 0)

__device__ __forceinline__ unsigned short f2bf(float f) {
    unsigned u = __builtin_bit_cast(unsigned, f);
    u += 0x7FFFu + ((u >> 16) & 1u);        // RTNE
    return (unsigned short)(u >> 16);
}
__device__ __forceinline__ void gl2lds16(const void* g, void* l) {
    __builtin_amdgcn_global_load_lds(
        (const __attribute__((address_space(1))) unsigned int*)g,
        (__attribute__((address_space(3))) unsigned int*)l, 16, 0, 0);
}

// ------------------------------- k_cvt_x -----------------------------------
__global__ __launch_bounds__(256) void k_cvt_x(const float* __restrict__ x,
                                               unsigned char* __restrict__ xt) {
    int v = blockIdx.x * 256 + threadIdx.x;
    int tile = v >> 10;
    int q = v & 1023;
    int row = q >> 3, c = q & 7;
    int mt = tile >> 3, ks = tile & 7;
    const float* sp = x + ((size_t)(mt * 128 + row)) * 512 + ks * 64 + c * 8;
    float4 v0 = *(const float4*)sp;
    float4 v1 = *(const float4*)(sp + 4);
    u16x8 o;
    o[0] = f2bf(v0.x); o[1] = f2bf(v0.y); o[2] = f2bf(v0.z); o[3] = f2bf(v0.w);
    o[4] = f2bf(v1.x); o[5] = f2bf(v1.y); o[6] = f2bf(v1.z); o[7] = f2bf(v1.w);
    *(u16x8*)(xt + (size_t)tile * 16384 + row * 128 + ((c ^ (row & 7)) << 4)) = o;
}

// ------------------------------- k_w_t_p ------------------------------------
__global__ __launch_bounds__(256) void k_w_t_p(const float* __restrict__ Wp,
                                               unsigned short* __restrict__ Wpt) {
    __shared__ float t[32][33];
    const int k0 = blockIdx.y * 32, n0 = blockIdx.x * 32;
#pragma unroll
    for (int j = 0; j < 4; ++j) {
        int i = threadIdx.x + 256 * j;
        int ky = i >> 5, nx = i & 31;
        t[ky][nx] = Wp[(size_t)(k0 + ky) * 512 + n0 + nx];
    }
    __syncthreads();
#pragma unroll
    for (int j = 0; j < 4; ++j) {
        int i = threadIdx.x + 256 * j;
        int ny = i >> 5, kx = i & 31;
        Wpt[(size_t)(n0 + ny) * 512 + k0 + kx] = f2bf(t[kx][ny]);
    }
}

// ------------------------------- k_w_tile -----------------------------------
// Wv -> wtl2 tile group (nt,ks): [0,8K) V. ([8K,12K) Sk, [12K,16K) Sq by k_akw)
__global__ __launch_bounds__(256) void k_w_tile(const float* __restrict__ Wv,
                                                unsigned char* __restrict__ wtl2) {
    const int ks = blockIdx.x, nt = blockIdx.y;
    unsigned char* dst = wtl2 + ((size_t)(nt * 8 + ks)) * 16384;
    const int row = threadIdx.x & 63;
#pragma unroll
    for (int cc = 0; cc < 2; ++cc) {
        int c = (threadIdx.x >> 6) + cc * 4;
        u16x8 o;
#pragma unroll
        for (int j = 0; j < 8; ++j)
            o[j] = f2bf(Wv[(size_t)(ks * 64 + c * 8 + j) * 512 + nt * 64 + row]);
        *(u16x8*)(dst + row * 128 + ((c ^ (row & 7)) << 4)) = o;
    }
}

// ------------------------------- k_akw --------------------------------------
// S[ag][kk] = sum_d at[ag][h*64+d] * W[ks*64+kk][h*64+d]; which: 0=Wk, 1=Wq.
// grid (8 ks, 8 h, 2 which), block 256 (row=tid>>3 ag, c8=tid&7)
__global__ __launch_bounds__(256) void k_akw(const float* __restrict__ at,
                                             const float* __restrict__ Wk,
                                             const float* __restrict__ Wq,
                                             unsigned char* __restrict__ wtl2) {
    const int ks = blockIdx.x, h = blockIdx.y, which = blockIdx.z;
    const float* W = which ? Wq : Wk;
    const int row = threadIdx.x >> 3, c8 = threadIdx.x & 7;
    const float* ar = at + row * 512 + h * 64;
    float accv[8];
#pragma unroll
    for (int j = 0; j < 8; ++j) {
        const float* wr = W + (size_t)(ks * 64 + c8 * 8 + j) * 512 + h * 64;
        float s = 0.f;
#pragma unroll 8
        for (int d = 0; d < 64; ++d) s += ar[d] * wr[d];
        accv[j] = s;
    }
    u16x8 o;
#pragma unroll
    for (int j = 0; j < 8; ++j) o[j] = f2bf(accv[j]);
    *(u16x8*)(wtl2 + ((size_t)(h * 8 + ks)) * 16384 + 8192 + which * 4096 +
              row * 128 + ((c8 ^ (row & 7)) << 4)) = o;
}

// ------------------------------- k_qkvs --------------------------------------
// BM=128, BN=128 (V64, Sk32, Sq32), BK=64. 4 waves, each 32 tok x all cols.
// Main loop = R4/R8 structure (gl2lds A 16KB + B 16KB, 2 barriers/step).
// Epilogue: V->LDS; key-score flash partial (M,L,PV per 128-tok chunk);
// q-score softmax in-register -> Qat tiled. grid 4096 (XCD-swz), block 256.
__global__ __launch_bounds__(256) void k_qkvs(const unsigned char* __restrict__ xt,
                                              const unsigned char* __restrict__ wtl2,
                                              const int* __restrict__ mask,
                                              unsigned char* __restrict__ Qat,
                                              float* __restrict__ part_pv,
                                              float* __restrict__ part_ml) {
    __shared__ __align__(16) unsigned char S_[32768];
    unsigned char* As = S_;                 // [0,16K) main
    unsigned char* Bs = S_ + 16384;         // [16K,32K) main
    const int tid = threadIdx.x, l = tid & 63, wid = tid >> 6;
    const int g = l >> 4, lr = l & 15;
    const int dd = blockIdx.x;
    const int nt = (dd >> 3) & 7;
    const int mt = (dd & 7) + ((dd >> 6) << 3);
    const int m0 = mt * 128;
    const int b = mt >> 7, chunk = mt & 127, bh = b * 8 + nt;

    f32x4 acc[2][8] = {};

    for (int ks = 0; ks < 8; ++ks) {
        const size_t abase = ((size_t)(mt * 8 + ks)) * 16384;
        const size_t bbase = ((size_t)(nt * 8 + ks)) * 16384;
#pragma unroll
        for (int i = 0; i < 4; ++i)
            gl2lds16(xt + abase + i * 4096 + tid * 16, As + i * 4096 + tid * 16);
#pragma unroll
        for (int i = 0; i < 4; ++i)
            gl2lds16(wtl2 + bbase + i * 4096 + tid * 16, Bs + i * 4096 + tid * 16);
        __syncthreads();

        bf16x8 af[2][2];
#pragma unroll
        for (int mf = 0; mf < 2; ++mf) {
            int row = wid * 32 + mf * 16 + lr;
#pragma unroll
            for (int k2 = 0; k2 < 2; ++k2)
                af[mf][k2] = *(const bf16x8*)(As + row * 128 + (((k2 * 4 + g) ^ (row & 7)) << 4));
        }
#pragma unroll
        for (int k2 = 0; k2 < 2; ++k2) {
#pragma unroll
            for (int nf = 0; nf < 8; ++nf) {
                const int reg = (nf < 4) ? 0 : (8192 + ((nf >> 1) & 1) * 4096 + 0);
                // nf 0-3: V rows 0..63 ; nf 4,5: Sk rows 0..31 ; nf 6,7: Sq rows 0..31
                const int sub = (nf < 4) ? nf : (nf & 1);
                const int regio = (nf < 4) ? 0 : (nf < 6 ? 8192 : 12288);
                int brow = sub * 16 + lr;
                bf16x8 bv = *(const bf16x8*)(Bs + regio + brow * 128 +
                                             (((k2 * 4 + g) ^ (brow & 7)) << 4));
                (void)reg;
#pragma unroll
                for (int mf = 0; mf < 2; ++mf)
                    acc[mf][nf] = MFMA16(af[mf][k2], bv, acc[mf][nf]);
            }
        }
        __syncthreads();
    }

    // ---------------- epilogue ----------------
    unsigned char* Psm_w = S_ + wid * 2048;          // [0,8K)   (over As, dead)
    unsigned char* Ev_w  = S_ + 8192 + wid * 4096;   // [8K,24K) (over As/Bs, dead)
    float* avsH = (float*)(S_ + 8192);               // overlays Ev (in-order per wave)
    float* redM = (float*)(S_ + 24576);              // [24576,+512) [4][32]
    float* redL = (float*)(S_ + 25088);              // +512

    // ---- fused q->agent softmax from Sq fragments -> Qat (no LDS) ----
    {
        const size_t qbase = ((size_t)(mt * 4 + (nt >> 1))) * 16384;
        const int c80 = (nt & 1) * 4 + (lr >> 3);
#pragma unroll
        for (int mf = 0; mf < 2; ++mf) {
#pragma unroll
            for (int r = 0; r < 4; ++r) {
                float v0 = acc[mf][6][r] * 0.125f, v1 = acc[mf][7][r] * 0.125f;
                float m = fmaxf(v0, v1);
                m = fmaxf(m, __shfl_xor(m, 1));
                m = fmaxf(m, __shfl_xor(m, 2));
                m = fmaxf(m, __shfl_xor(m, 4));
                m = fmaxf(m, __shfl_xor(m, 8));
                float e0 = __expf(v0 - m), e1 = __expf(v1 - m);
                float s = e0 + e1;
                s += __shfl_xor(s, 1);
                s += __shfl_xor(s, 2);
                s += __shfl_xor(s, 4);
                s += __shfl_xor(s, 8);
                float inv = 1.0f / s;
                int row = wid * 32 + mf * 16 + g * 4 + r;
                size_t rb = qbase + row * 128 + (lr & 7) * 2;
                *(unsigned short*)(Qat + rb + ((c80 ^ (row & 7)) << 4)) = f2bf(e0 * inv);
                *(unsigned short*)(Qat + rb + (((c80 + 2) ^ (row & 7)) << 4)) = f2bf(e1 * inv);
            }
        }
    }

    // ---- V -> Ev (per-wave [64 d][32 tok], u16x4 vector writes) ----
#pragma unroll
    for (int mf = 0; mf < 2; ++mf)
#pragma unroll
        for (int vf = 0; vf < 4; ++vf) {
            int d5 = vf * 16 + lr;
            u16x4 vv;
            vv[0] = f2bf(acc[mf][vf][0]); vv[1] = f2bf(acc[mf][vf][1]);
            vv[2] = f2bf(acc[mf][vf][2]); vv[3] = f2bf(acc[mf][vf][3]);
            *(u16x4*)(Ev_w + d5 * 64 + ((mf * 32 + g * 8) ^ ((d5 & 3) << 4))) = vv;
        }

    // ---- key scores: scale + mask ----
    float sc2[2][2][4];
#pragma unroll
    for (int mf = 0; mf < 2; ++mf) {
        int4 mv = *(const int4*)(mask + m0 + wid * 32 + mf * 16 + g * 4);
        int mvr[4] = {mv.x, mv.y, mv.z, mv.w};
#pragma unroll
        for (int sf = 0; sf < 2; ++sf)
#pragma unroll
            for (int r = 0; r < 4; ++r)
                sc2[mf][sf][r] = (mvr[r] > 0) ? acc[mf][4 + sf][r] * 0.125f : -1.0e9f;
    }
    // wave max per agent, then block max via LDS
    float mw[2];
#pragma unroll
    for (int sf = 0; sf < 2; ++sf) {
        float m = sc2[0][sf][0];
#pragma unroll
        for (int mf = 0; mf < 2; ++mf)
#pragma unroll
            for (int r = 0; r < 4; ++r) m = fmaxf(m, sc2[mf][sf][r]);
        m = fmaxf(m, __shfl_xor(m, 16));
        m = fmaxf(m, __shfl_xor(m, 32));
        mw[sf] = m;
    }
    if (g == 0) { redM[wid * 32 + lr] = mw[0]; redM[wid * 32 + 16 + lr] = mw[1]; }
    __syncthreads();
    float Mb[2];
#pragma unroll
    for (int sf = 0; sf < 2; ++sf) {
        int ag = sf * 16 + lr;
        Mb[sf] = fmaxf(fmaxf(redM[ag], redM[32 + ag]), fmaxf(redM[64 + ag], redM[96 + ag]));
    }
    // P = exp(s-Mb) -> Psm ; L partials
    float le[2] = {0.f, 0.f};
#pragma unroll
    for (int mf = 0; mf < 2; ++mf)
#pragma unroll
        for (int sf = 0; sf < 2; ++sf)
#pragma unroll
            for (int r = 0; r < 4; ++r) {
                float p = __expf(sc2[mf][sf][r] - Mb[sf]);
                le[sf] += p;
                int ag = sf * 16 + lr;
                int tk = mf * 16 + g * 4 + r;
                *(unsigned short*)(Psm_w + ag * 64 + ((2 * tk) ^ (((ag >> 2) & 3) << 4))) = f2bf(p);
            }
#pragma unroll
    for (int sf = 0; sf < 2; ++sf) {
        le[sf] += __shfl_xor(le[sf], 16);
        le[sf] += __shfl_xor(le[sf], 32);
    }
    if (g == 0) { redL[wid * 32 + lr] = le[0]; redL[wid * 32 + 16 + lr] = le[1]; }

    // ---- P @ V (one K=32 MFMA step; within-wave LDS, in-order) ----
    bf16x8 pa[2];
#pragma unroll
    for (int agf = 0; agf < 2; ++agf) {
        int ag = agf * 16 + lr;
        pa[agf] = *(const bf16x8*)(Psm_w + ag * 64 + ((g * 16) ^ (((ag >> 2) & 3) << 4)));
    }
    f32x4 pv[2][4] = {};
#pragma unroll
    for (int vf = 0; vf < 4; ++vf) {
        int d5 = vf * 16 + lr;
        bf16x8 bv = *(const bf16x8*)(Ev_w + d5 * 64 + ((g * 16) ^ ((d5 & 3) << 4)));
#pragma unroll
        for (int agf = 0; agf < 2; ++agf)
            pv[agf][vf] = MFMA16(pa[agf], bv, pv[agf][vf]);
    }

    // ---- cross-wave PV reduce (avsH overlays Ev; per-wave in-order safe) ----
    float* pout = part_pv + ((size_t)bh * 128 + chunk) * 2048;
#pragma unroll
    for (int agf = 0; agf < 2; ++agf) {
#pragma unroll
        for (int vf = 0; vf < 4; ++vf)
#pragma unroll
            for (int r = 0; r < 4; ++r)
                avsH[wid * 1024 + (g * 4 + r) * 64 + vf * 16 + lr] = pv[agf][vf][r];
        __syncthreads();
#pragma unroll
        for (int j = 0; j < 4; ++j) {
            int idx = tid + 256 * j;
            pout[agf * 1024 + idx] = avsH[idx] + avsH[1024 + idx] +
                                     avsH[2048 + idx] + avsH[3072 + idx];
        }
        if (agf == 0) __syncthreads();
    }
    // M,L partials
    if (wid == 0 && g == 0) {
        size_t o = ((size_t)bh * 128 + chunk) * 64;
        float L0 = redL[lr] + redL[32 + lr] + redL[64 + lr] + redL[96 + lr];
        float L1 = redL[16 + lr] + redL[48 + lr] + redL[80 + lr] + redL[112 + lr];
        part_ml[o + lr * 2] = Mb[0];
        part_ml[o + lr * 2 + 1] = L0;
        part_ml[o + (16 + lr) * 2] = Mb[1];
        part_ml[o + (16 + lr) * 2 + 1] = L1;
    }
}

// ------------------------------- k_agent_comb --------------------------------
// merge 128 chunks per (b,h). grid (8 agent-groups, 32 bh), block 256.
__global__ __launch_bounds__(256) void k_agent_comb(const float* __restrict__ part_pv,
                                                    const float* __restrict__ part_ml,
                                                    unsigned short* __restrict__ avbf) {
    __shared__ float scl[128][4];
    __shared__ float iLg[4], Mg[4];
    const int tid = threadIdx.x;
    const int ag0 = blockIdx.x * 4, bh = blockIdx.y;
    if (tid < 4) {
        int ag = ag0 + tid;
        const float* ml = part_ml + (size_t)bh * 8192 + ag * 2;
        float M = -3.0e38f;
#pragma unroll 4
        for (int c = 0; c < 128; ++c) M = fmaxf(M, ml[c * 64]);
        float L = 0.f;
#pragma unroll 4
        for (int c = 0; c < 128; ++c) L += __expf(ml[c * 64] - M) * ml[c * 64 + 1];
        Mg[tid] = M; iLg[tid] = 1.0f / L;
    }
    __syncthreads();
#pragma unroll
    for (int it = 0; it < 2; ++it) {
        int idx = tid + 256 * it;
        int c = idx >> 2, agl = idx & 3;
        scl[c][agl] = __expf(part_ml[(size_t)bh * 8192 + (size_t)c * 64 + (ag0 + agl) * 2] - Mg[agl]);
    }
    __syncthreads();
    const int agl = tid >> 6, d5 = tid & 63;
    const float* pv = part_pv + (size_t)bh * 128 * 2048 + (size_t)(ag0 + agl) * 64 + d5;
    float a = 0.f;
#pragma unroll 4
    for (int c = 0; c < 128; ++c) a += scl[c][agl] * pv[(size_t)c * 2048];
    avbf[(size_t)bh * 2048 + (size_t)(ag0 + agl) * 64 + d5] = f2bf(a * iLg[agl]);
}

// ------------------------------- k_avp ----------------------------------------
__global__ __launch_bounds__(64) void k_avp(const unsigned short* __restrict__ avbf,
                                            const unsigned short* __restrict__ Wpt,
                                            unsigned char* __restrict__ AVPt) {
    const int l = threadIdx.x & 63;
    const int bh = blockIdx.x, b = bh >> 3, h = bh & 7;
    const int g = l >> 4, lr = l & 15;
    bf16x8 avf[2][2];
#pragma unroll
    for (int mf = 0; mf < 2; ++mf)
#pragma unroll
        for (int ks = 0; ks < 2; ++ks)
            avf[mf][ks] = *(const bf16x8*)(avbf + (size_t)bh * 2048 + (mf * 16 + lr) * 64 + ks * 32 + g * 8);
    const int kst = h >> 1;
#pragma unroll 4
    for (int nf = 0; nf < 32; ++nf) {
        int j = nf * 16 + lr;
        bf16x8 w0 = *(const bf16x8*)(Wpt + (size_t)j * 512 + h * 64 + g * 8);
        bf16x8 w1 = *(const bf16x8*)(Wpt + (size_t)j * 512 + h * 64 + 32 + g * 8);
        int jt = j >> 7, row = j & 127;
#pragma unroll
        for (int mf = 0; mf < 2; ++mf) {
            f32x4 z = {0.f, 0.f, 0.f, 0.f};
            f32x4 acc = MFMA16(avf[mf][0], w0, z);
            acc = MFMA16(avf[mf][1], w1, acc);
            u16x4 o;
            o[0] = f2bf(acc[0]); o[1] = f2bf(acc[1]); o[2] = f2bf(acc[2]); o[3] = f2bf(acc[3]);
            int c8 = (h & 1) * 4 + mf * 2 + (g >> 1);
            size_t byte = ((size_t)((b * 4 + jt) * 4 + kst)) * 16384 + row * 128 +
                          ((c8 ^ (row & 7)) << 4) + (g & 1) * 8;
            *(u16x4*)(AVPt + byte) = o;
        }
    }
}

// ------------------------------- k_out -----------------------------------------
__global__ __launch_bounds__(256) void k_out(const unsigned char* __restrict__ Qat,
                                             const unsigned char* __restrict__ AVPt,
                                             const int* __restrict__ mask,
                                             float* __restrict__ out) {
    __shared__ __align__(16) unsigned char As[16384];
    __shared__ __align__(16) unsigned char Bs[16384];
    const int tid = threadIdx.x, l = tid & 63, wid = tid >> 6;
    const int wm = wid >> 1, wn = wid & 1;
    const int g = l >> 4, lr = l & 15;
    const int d = blockIdx.x;
    const int nt = (d >> 3) & 3;
    const int mt = (d & 7) + ((d >> 5) << 3);
    const int m0 = mt * 128, j0 = nt * 128;
    const int b = m0 >> 14;
    f32x4 acc[4][4] = {};

    for (int ks = 0; ks < 4; ++ks) {
        const size_t abase = ((size_t)(mt * 4 + ks)) * 16384;
        const size_t bbase = ((size_t)((b * 4 + nt) * 4 + ks)) * 16384;
#pragma unroll
        for (int i = 0; i < 4; ++i) {
            gl2lds16(Qat + abase + i * 4096 + tid * 16, As + i * 4096 + tid * 16);
            gl2lds16(AVPt + bbase + i * 4096 + tid * 16, Bs + i * 4096 + tid * 16);
        }
        __syncthreads();
        bf16x8 af[4][2];
#pragma unroll
        for (int mf = 0; mf < 4; ++mf) {
            int row = wm * 64 + mf * 16 + lr;
#pragma unroll
            for (int k2 = 0; k2 < 2; ++k2)
                af[mf][k2] = *(const bf16x8*)(As + row * 128 + (((k2 * 4 + g) ^ (row & 7)) << 4));
        }
#pragma unroll
        for (int k2 = 0; k2 < 2; ++k2) {
#pragma unroll
            for (int nf = 0; nf < 4; ++nf) {
                int brow = wn * 64 + nf * 16 + lr;
                bf16x8 bv = *(const bf16x8*)(Bs + brow * 128 + (((k2 * 4 + g) ^ (brow & 7)) << 4));
#pragma unroll
                for (int mf = 0; mf < 4; ++mf)
                    acc[mf][nf] = MFMA16(af[mf][k2], bv, acc[mf][nf]);
            }
        }
        __syncthreads();
    }
#pragma unroll
    for (int mf = 0; mf < 4; ++mf) {
        int trow = m0 + wm * 64 + mf * 16 + g * 4;
#pragma unroll
        for (int r = 0; r < 4; ++r) {
            float mv = (mask[trow + r] > 0) ? 1.0f : 0.0f;
#pragma unroll
            for (int nf = 0; nf < 4; ++nf) {
                int j = j0 + wn * 64 + nf * 16 + lr;
                out[(size_t)(trow + r) * 512 + j] = acc[mf][nf][r] * mv;
            }
        }
    }
}

// ------------------------------- launch -----------------------------------------
extern "C" void kernel_launch(void* const* d_in, const int* in_sizes, int n_in,
                              void* d_out, int out_size, void* d_ws, size_t ws_size,
                              hipStream_t stream) {
    const float* x  = (const float*)d_in[0];
    const int*  mk  = (const int*)d_in[1];
    const float* at = (const float*)d_in[2];
    const float* Wq = (const float*)d_in[3];
    const float* Wk = (const float*)d_in[4];
    const float* Wv = (const float*)d_in[5];
    const float* Wp = (const float*)d_in[6];
    float* out = (float*)d_out;
    char* ws = (char*)d_ws;

    unsigned char*  xt    = (unsigned char*)(ws);                        // [0,64) tiled x (live through k_qkvs)
    float* part_pv = (float*)(ws + ((size_t)64 << 20));                  // [64,98) 33.5 MiB
    float* part_ml = (float*)(ws + ((size_t)100 << 20));                 // [100,101) 1 MiB
    unsigned char*  Qat   = (unsigned char*)(ws + ((size_t)192 << 20));  // [192,224) tiled (NOT aliasing xt!)
    unsigned short* Wpt   = (unsigned short*)(ws + ((size_t)256 << 20)); // [256,256.5)
    unsigned char*  wtl2  = (unsigned char*)(ws + ((size_t)258 << 20));  // [258,259) 1 MiB
    unsigned short* avbf  = (unsigned short*)(ws + ((size_t)259 << 20) + (576 << 10));
    unsigned char*  AVPt  = (unsigned char*)(ws + ((size_t)260 << 20));  // [260,261)

    k_cvt_x<<<16384, 256, 0, stream>>>(x, xt);
    k_w_t_p<<<dim3(16, 16), 256, 0, stream>>>(Wp, Wpt);
    k_w_tile<<<dim3(8, 8), 256, 0, stream>>>(Wv, wtl2);
    k_akw<<<dim3(8, 8, 2), 256, 0, stream>>>(at, Wk, Wq, wtl2);
    k_qkvs<<<4096, 256, 0, stream>>>(xt, wtl2, mk, Qat, part_pv, part_ml);
    k_agent_comb<<<dim3(8, 32), 256, 0, stream>>>(part_pv, part_ml, avbf);
    k_avp<<<32, 64, 0, stream>>>(avbf, Wpt, AVPt);
    k_out<<<2048, 256, 0, stream>>>(Qat, AVPt, mk, out);
}

// Round 10
// 241.463 us; speedup vs baseline: 1.4031x; 1.0126x over previous
//
#include <hip/hip_runtime.h>

// ---------------------------------------------------------------------------
// MaskedSuperAttention (agent attention), B=4 N=16384 C=512 H=8 HD=64 NA=32
// R9 math: score1 = x·(Wk@a^T), score2 = x·(Wq@a^T) => Q,K,V never hit HBM.
// R10: k_qkvs was LDS-BW-bound (80KB reads/step/block) with 854cyc/block of
// epilogue bank conflicts. Fix: 2x2 wave grid (64KB reads/step), stride-144B
// conflict-free P/Ev epilogue tiles, u16x4 LDS writes, PV split over 4 waves.
//   k_cvt_x      : x f32 -> xt bf16 TILED (128x64 swizzled tiles)
//   k_w_t_p      : Wproj -> Wpt bf16 [n][k] (for k_avp)
//   k_w_tile     : Wv -> wtl2 tiled-swizzled (B operand V region)
//   k_akw        : Sk = Wk@a^T, Sq = Wq@a^T -> wtl2 score regions
//   k_qkvs       : GEMM x@[Wv|akw|aqw] (BN=128) ; epilogue: flash partial
//                  (M,L,PV) per 128-tok chunk + q-softmax -> Qat tiled.
//   k_agent_comb : merge 128 partials per (b,h) -> agent_v bf16
//   k_avp        : AVP = agent_v @ Wproj -> AVPt TILED
//   k_out        : out = (Qattn @ AVPt) * keymask
// Tiled layout: tile 128x64 (16KiB); byte(row,c8)= row*128 + ((c8^(row&7))<<4)
// ---------------------------------------------------------------------------

typedef float  f32x4   __attribute__((ext_vector_type(4)));
typedef short  bf16x8  __attribute__((ext_vector_type(8)));
typedef unsigned short u16x4 __attribute__((ext_vector_type(4)));
typedef unsigned short u16x8 __attribute__((ext_vector_type(8)));

#define MFMA16(a, b, c) __builtin_amdgcn_mfma_f32_16x16x32_bf16((a), (b), (c), 0, 0, 0)

__device__ __forceinline__ unsigned short f2bf(float f) {
    unsigned u = __builtin_bit_cast(unsigned, f);
    u += 0x7FFFu + ((u >> 16) & 1u);        // RTNE
    return (unsigned short)(u >> 16);
}
__device__ __forceinline__ void gl2lds16(const void* g, void* l) {
    __builtin_amdgcn_global_load_lds(
        (const __attribute__((address_space(1))) unsigned int*)g,
        (__attribute__((address_space(3))) unsigned int*)l, 16, 0, 0);
}

// ------------------------------- k_cvt_x -----------------------------------
__global__ __launch_bounds__(256) void k_cvt_x(const float* __restrict__ x,
                                               unsigned char* __restrict__ xt) {
    int v = blockIdx.x * 256 + threadIdx.x;
    int tile = v >> 10;
    int q = v & 1023;
    int row = q >> 3, c = q & 7;
    int mt = tile >> 3, ks = tile & 7;
    const float* sp = x + ((size_t)(mt * 128 + row)) * 512 + ks * 64 + c * 8;
    float4 v0 = *(const float4*)sp;
    float4 v1 = *(const float4*)(sp + 4);
    u16x8 o;
    o[0] = f2bf(v0.x); o[1] = f2bf(v0.y); o[2] = f2bf(v0.z); o[3] = f2bf(v0.w);
    o[4] = f2bf(v1.x); o[5] = f2bf(v1.y); o[6] = f2bf(v1.z); o[7] = f2bf(v1.w);
    *(u16x8*)(xt + (size_t)tile * 16384 + row * 128 + ((c ^ (row & 7)) << 4)) = o;
}

// ------------------------------- k_w_t_p ------------------------------------
__global__ __launch_bounds__(256) void k_w_t_p(const float* __restrict__ Wp,
                                               unsigned short* __restrict__ Wpt) {
    __shared__ float t[32][33];
    const int k0 = blockIdx.y * 32, n0 = blockIdx.x * 32;
#pragma unroll
    for (int j = 0; j < 4; ++j) {
        int i = threadIdx.x + 256 * j;
        int ky = i >> 5, nx = i & 31;
        t[ky][nx] = Wp[(size_t)(k0 + ky) * 512 + n0 + nx];
    }
    __syncthreads();
#pragma unroll
    for (int j = 0; j < 4; ++j) {
        int i = threadIdx.x + 256 * j;
        int ny = i >> 5, kx = i & 31;
        Wpt[(size_t)(n0 + ny) * 512 + k0 + kx] = f2bf(t[kx][ny]);
    }
}

// ------------------------------- k_w_tile -----------------------------------
// Wv -> wtl2 tile group (nt,ks): [0,8K) V. ([8K,12K) Sk, [12K,16K) Sq by k_akw)
__global__ __launch_bounds__(256) void k_w_tile(const float* __restrict__ Wv,
                                                unsigned char* __restrict__ wtl2) {
    const int ks = blockIdx.x, nt = blockIdx.y;
    unsigned char* dst = wtl2 + ((size_t)(nt * 8 + ks)) * 16384;
    const int row = threadIdx.x & 63;
#pragma unroll
    for (int cc = 0; cc < 2; ++cc) {
        int c = (threadIdx.x >> 6) + cc * 4;
        u16x8 o;
#pragma unroll
        for (int j = 0; j < 8; ++j)
            o[j] = f2bf(Wv[(size_t)(ks * 64 + c * 8 + j) * 512 + nt * 64 + row]);
        *(u16x8*)(dst + row * 128 + ((c ^ (row & 7)) << 4)) = o;
    }
}

// ------------------------------- k_akw --------------------------------------
// S[ag][kk] = sum_d at[ag][h*64+d] * W[ks*64+kk][h*64+d]; which: 0=Wk, 1=Wq.
__global__ __launch_bounds__(256) void k_akw(const float* __restrict__ at,
                                             const float* __restrict__ Wk,
                                             const float* __restrict__ Wq,
                                             unsigned char* __restrict__ wtl2) {
    const int ks = blockIdx.x, h = blockIdx.y, which = blockIdx.z;
    const float* W = which ? Wq : Wk;
    const int row = threadIdx.x >> 3, c8 = threadIdx.x & 7;
    const float* ar = at + row * 512 + h * 64;
    float accv[8];
#pragma unroll
    for (int j = 0; j < 8; ++j) {
        const float* wr = W + (size_t)(ks * 64 + c8 * 8 + j) * 512 + h * 64;
        float s = 0.f;
#pragma unroll 8
        for (int d = 0; d < 64; ++d) s += ar[d] * wr[d];
        accv[j] = s;
    }
    u16x8 o;
#pragma unroll
    for (int j = 0; j < 8; ++j) o[j] = f2bf(accv[j]);
    *(u16x8*)(wtl2 + ((size_t)(h * 8 + ks)) * 16384 + 8192 + which * 4096 +
              row * 128 + ((c8 ^ (row & 7)) << 4)) = o;
}

// ------------------------------- k_qkvs --------------------------------------
// BM=128, BN=128 (V64, Sk32, Sq32), BK=64. 2x2 wave grid: wave (wm,wn) owns
// rows wm*64..+64 x cols wn*64..+64 -> per-wave LDS reads 16 (was 20).
// Epilogue: stride-144B P/Ev tiles (2-way bank alias = free), u16x4 writes,
// PV split into 4 K=32 slices (one per wave), avsH overlays dead regions.
// grid 4096 (XCD-swz), block 256, LDS 32768.
__global__ __launch_bounds__(256) void k_qkvs(const unsigned char* __restrict__ xt,
                                              const unsigned char* __restrict__ wtl2,
                                              const int* __restrict__ mask,
                                              unsigned char* __restrict__ Qat,
                                              float* __restrict__ part_pv,
                                              float* __restrict__ part_ml) {
    __shared__ __align__(16) unsigned char S_[32768];
    unsigned char* As = S_;                 // [0,16K) main A
    unsigned char* Bs = S_ + 16384;         // [16K,32K) main B
    const int tid = threadIdx.x, l = tid & 63, wid = tid >> 6;
    const int g = l >> 4, lr = l & 15;
    const int wm = wid >> 1, wn = wid & 1;
    const int dd = blockIdx.x;
    const int nt = (dd >> 3) & 7;
    const int mt = (dd & 7) + ((dd >> 6) << 3);
    const int m0 = mt * 128;
    const int b = mt >> 7, chunk = mt & 127, bh = b * 8 + nt;

    f32x4 acc[4][4] = {};

    for (int ks = 0; ks < 8; ++ks) {
        const size_t abase = ((size_t)(mt * 8 + ks)) * 16384;
        const size_t bbase = ((size_t)(nt * 8 + ks)) * 16384;
#pragma unroll
        for (int i = 0; i < 4; ++i)
            gl2lds16(xt + abase + i * 4096 + tid * 16, As + i * 4096 + tid * 16);
#pragma unroll
        for (int i = 0; i < 4; ++i)
            gl2lds16(wtl2 + bbase + i * 4096 + tid * 16, Bs + i * 4096 + tid * 16);
        __syncthreads();

        bf16x8 af[4][2];
#pragma unroll
        for (int mf = 0; mf < 4; ++mf) {
            int row = wm * 64 + mf * 16 + lr;
#pragma unroll
            for (int k2 = 0; k2 < 2; ++k2)
                af[mf][k2] = *(const bf16x8*)(As + row * 128 + (((k2 * 4 + g) ^ (row & 7)) << 4));
        }
#pragma unroll
        for (int k2 = 0; k2 < 2; ++k2) {
#pragma unroll
            for (int nf = 0; nf < 4; ++nf) {
                // wn=0: V cols (regio 0, rows nf*16)
                // wn=1: nf 0,1 -> Sk (regio 8192); nf 2,3 -> Sq (regio 12288)
                const int regio = wn ? (8192 + (nf >> 1) * 4096) : 0;
                const int brow = (wn ? ((nf & 1) * 16) : (nf * 16)) + lr;
                bf16x8 bv = *(const bf16x8*)(Bs + regio + brow * 128 +
                                             (((k2 * 4 + g) ^ (brow & 7)) << 4));
#pragma unroll
                for (int mf = 0; mf < 4; ++mf)
                    acc[mf][nf] = MFMA16(af[mf][k2], bv, acc[mf][nf]);
            }
        }
        __syncthreads();
    }

    // ---------------- epilogue ----------------
    // LDS: P [2 halves][32 ag][144B] @0..9216 ; Ev [2][64 d][144B] @9216..27648
    //      redM [2][32] @27648 ; redL [2][32] @27904 ; avsH overlays [0,16K) post-PV.
    unsigned char* Ph0 = S_;
    unsigned char* Evh = S_ + 9216;
    float* redM = (float*)(S_ + 27648);
    float* redL = (float*)(S_ + 27904);
    float* avsH = (float*)S_;

    float sc2[4][2][4];
    float Mb[2];

    if (wn == 0) {
        // ---- V waves: acc[mf][vf] -> Ev half wm ([64 d][64 tok], stride 144) ----
        unsigned char* Ev = Evh + wm * 9216;
#pragma unroll
        for (int mf = 0; mf < 4; ++mf)
#pragma unroll
            for (int vf = 0; vf < 4; ++vf) {
                int d5 = vf * 16 + lr;
                u16x4 vv;
                vv[0] = f2bf(acc[mf][vf][0]); vv[1] = f2bf(acc[mf][vf][1]);
                vv[2] = f2bf(acc[mf][vf][2]); vv[3] = f2bf(acc[mf][vf][3]);
                *(u16x4*)(Ev + d5 * 144 + mf * 32 + g * 8) = vv;
            }
    } else {
        // ---- score waves: q-softmax from Sq (acc[mf][2..3]) -> Qat tiled ----
        const size_t qbase = ((size_t)(mt * 4 + (nt >> 1))) * 16384;
        const int c80 = (nt & 1) * 4 + (lr >> 3);
#pragma unroll
        for (int mf = 0; mf < 4; ++mf) {
#pragma unroll
            for (int r = 0; r < 4; ++r) {
                float v0 = acc[mf][2][r] * 0.125f, v1 = acc[mf][3][r] * 0.125f;
                float m = fmaxf(v0, v1);
                m = fmaxf(m, __shfl_xor(m, 1));
                m = fmaxf(m, __shfl_xor(m, 2));
                m = fmaxf(m, __shfl_xor(m, 4));
                m = fmaxf(m, __shfl_xor(m, 8));
                float e0 = __expf(v0 - m), e1 = __expf(v1 - m);
                float s = e0 + e1;
                s += __shfl_xor(s, 1);
                s += __shfl_xor(s, 2);
                s += __shfl_xor(s, 4);
                s += __shfl_xor(s, 8);
                float inv = 1.0f / s;
                int row = wm * 64 + mf * 16 + g * 4 + r;
                size_t rb = qbase + row * 128 + (lr & 7) * 2;
                *(unsigned short*)(Qat + rb + ((c80 ^ (row & 7)) << 4)) = f2bf(e0 * inv);
                *(unsigned short*)(Qat + rb + (((c80 + 2) ^ (row & 7)) << 4)) = f2bf(e1 * inv);
            }
        }
        // ---- masked key scores (acc[mf][0..1]) + wave max per agent ----
#pragma unroll
        for (int mf = 0; mf < 4; ++mf) {
            int4 mv = *(const int4*)(mask + m0 + wm * 64 + mf * 16 + g * 4);
            int mvr[4] = {mv.x, mv.y, mv.z, mv.w};
#pragma unroll
            for (int sf = 0; sf < 2; ++sf)
#pragma unroll
                for (int r = 0; r < 4; ++r)
                    sc2[mf][sf][r] = (mvr[r] > 0) ? acc[mf][sf][r] * 0.125f : -1.0e9f;
        }
#pragma unroll
        for (int sf = 0; sf < 2; ++sf) {
            float m = sc2[0][sf][0];
#pragma unroll
            for (int mf = 0; mf < 4; ++mf)
#pragma unroll
                for (int r = 0; r < 4; ++r) m = fmaxf(m, sc2[mf][sf][r]);
            m = fmaxf(m, __shfl_xor(m, 16));
            m = fmaxf(m, __shfl_xor(m, 32));
            if (g == 0) redM[wm * 32 + sf * 16 + lr] = m;
        }
    }
    __syncthreads();    // redM + Ev visible

    if (wn == 1) {
        // ---- block max, P = exp(s-Mb) -> P LDS (u16x4), L partials ----
        float le[2] = {0.f, 0.f};
#pragma unroll
        for (int sf = 0; sf < 2; ++sf) {
            int ag = sf * 16 + lr;
            Mb[sf] = fmaxf(redM[ag], redM[32 + ag]);
        }
        unsigned char* Ph = Ph0 + wm * 4608;
#pragma unroll
        for (int mf = 0; mf < 4; ++mf)
#pragma unroll
            for (int sf = 0; sf < 2; ++sf) {
                u16x4 p4;
#pragma unroll
                for (int r = 0; r < 4; ++r) {
                    float p = __expf(sc2[mf][sf][r] - Mb[sf]);
                    le[sf] += p;
                    p4[r] = f2bf(p);
                }
                int ag = sf * 16 + lr;
                *(u16x4*)(Ph + ag * 144 + mf * 32 + g * 8) = p4;
            }
#pragma unroll
        for (int sf = 0; sf < 2; ++sf) {
            le[sf] += __shfl_xor(le[sf], 16);
            le[sf] += __shfl_xor(le[sf], 32);
            if (g == 0) redL[wm * 32 + sf * 16 + lr] = le[sf];
        }
    }
    __syncthreads();    // P + redL visible

    // ---- PV: each wave one K=32 slice (half=wm, ks-sub=wn) ----
    const unsigned char* Ph = Ph0 + wm * 4608;
    const unsigned char* Ev = Evh + wm * 9216;
    bf16x8 pa[2];
#pragma unroll
    for (int agf = 0; agf < 2; ++agf) {
        int ag = agf * 16 + lr;
        pa[agf] = *(const bf16x8*)(Ph + ag * 144 + wn * 64 + g * 16);
    }
    f32x4 pv[2][4] = {};
#pragma unroll
    for (int vf = 0; vf < 4; ++vf) {
        int d5 = vf * 16 + lr;
        bf16x8 bv = *(const bf16x8*)(Ev + d5 * 144 + wn * 64 + g * 16);
#pragma unroll
        for (int agf = 0; agf < 2; ++agf)
            pv[agf][vf] = MFMA16(pa[agf], bv, pv[agf][vf]);
    }
    __syncthreads();    // PV reads done; safe to overlay avsH

    // ---- cross-wave PV reduce (2 rounds of 16 agents) ----
    float* pout = part_pv + ((size_t)bh * 128 + chunk) * 2048;
#pragma unroll
    for (int agf = 0; agf < 2; ++agf) {
#pragma unroll
        for (int vf = 0; vf < 4; ++vf)
#pragma unroll
            for (int r = 0; r < 4; ++r)
                avsH[wid * 1024 + (g * 4 + r) * 64 + vf * 16 + lr] = pv[agf][vf][r];
        __syncthreads();
#pragma unroll
        for (int j = 0; j < 4; ++j) {
            int idx = tid + 256 * j;
            pout[agf * 1024 + idx] = avsH[idx] + avsH[1024 + idx] +
                                     avsH[2048 + idx] + avsH[3072 + idx];
        }
        if (agf == 0) __syncthreads();
    }
    // ---- M,L partials ----
    if (wid == 1 && g == 0) {
        size_t o = ((size_t)bh * 128 + chunk) * 64;
        float L0 = redL[lr] + redL[32 + lr];
        float L1 = redL[16 + lr] + redL[48 + lr];
        part_ml[o + lr * 2] = Mb[0];
        part_ml[o + lr * 2 + 1] = L0;
        part_ml[o + (16 + lr) * 2] = Mb[1];
        part_ml[o + (16 + lr) * 2 + 1] = L1;
    }
}

// ------------------------------- k_agent_comb --------------------------------
__global__ __launch_bounds__(256) void k_agent_comb(const float* __restrict__ part_pv,
                                                    const float* __restrict__ part_ml,
                                                    unsigned short* __restrict__ avbf) {
    __shared__ float scl[128][4];
    __shared__ float iLg[4], Mg[4];
    const int tid = threadIdx.x;
    const int ag0 = blockIdx.x * 4, bh = blockIdx.y;
    if (tid < 4) {
        int ag = ag0 + tid;
        const float* ml = part_ml + (size_t)bh * 8192 + ag * 2;
        float M = -3.0e38f;
#pragma unroll 4
        for (int c = 0; c < 128; ++c) M = fmaxf(M, ml[c * 64]);
        float L = 0.f;
#pragma unroll 4
        for (int c = 0; c < 128; ++c) L += __expf(ml[c * 64] - M) * ml[c * 64 + 1];
        Mg[tid] = M; iLg[tid] = 1.0f / L;
    }
    __syncthreads();
#pragma unroll
    for (int it = 0; it < 2; ++it) {
        int idx = tid + 256 * it;
        int c = idx >> 2, agl = idx & 3;
        scl[c][agl] = __expf(part_ml[(size_t)bh * 8192 + (size_t)c * 64 + (ag0 + agl) * 2] - Mg[agl]);
    }
    __syncthreads();
    const int agl = tid >> 6, d5 = tid & 63;
    const float* pv = part_pv + (size_t)bh * 128 * 2048 + (size_t)(ag0 + agl) * 64 + d5;
    float a = 0.f;
#pragma unroll 4
    for (int c = 0; c < 128; ++c) a += scl[c][agl] * pv[(size_t)c * 2048];
    avbf[(size_t)bh * 2048 + (size_t)(ag0 + agl) * 64 + d5] = f2bf(a * iLg[agl]);
}

// ------------------------------- k_avp ----------------------------------------
__global__ __launch_bounds__(64) void k_avp(const unsigned short* __restrict__ avbf,
                                            const unsigned short* __restrict__ Wpt,
                                            unsigned char* __restrict__ AVPt) {
    const int l = threadIdx.x & 63;
    const int bh = blockIdx.x, b = bh >> 3, h = bh & 7;
    const int g = l >> 4, lr = l & 15;
    bf16x8 avf[2][2];
#pragma unroll
    for (int mf = 0; mf < 2; ++mf)
#pragma unroll
        for (int ks = 0; ks < 2; ++ks)
            avf[mf][ks] = *(const bf16x8*)(avbf + (size_t)bh * 2048 + (mf * 16 + lr) * 64 + ks * 32 + g * 8);
    const int kst = h >> 1;
#pragma unroll 4
    for (int nf = 0; nf < 32; ++nf) {
        int j = nf * 16 + lr;
        bf16x8 w0 = *(const bf16x8*)(Wpt + (size_t)j * 512 + h * 64 + g * 8);
        bf16x8 w1 = *(const bf16x8*)(Wpt + (size_t)j * 512 + h * 64 + 32 + g * 8);
        int jt = j >> 7, row = j & 127;
#pragma unroll
        for (int mf = 0; mf < 2; ++mf) {
            f32x4 z = {0.f, 0.f, 0.f, 0.f};
            f32x4 acc = MFMA16(avf[mf][0], w0, z);
            acc = MFMA16(avf[mf][1], w1, acc);
            u16x4 o;
            o[0] = f2bf(acc[0]); o[1] = f2bf(acc[1]); o[2] = f2bf(acc[2]); o[3] = f2bf(acc[3]);
            int c8 = (h & 1) * 4 + mf * 2 + (g >> 1);
            size_t byte = ((size_t)((b * 4 + jt) * 4 + kst)) * 16384 + row * 128 +
                          ((c8 ^ (row & 7)) << 4) + (g & 1) * 8;
            *(u16x4*)(AVPt + byte) = o;
        }
    }
}

// ------------------------------- k_out -----------------------------------------
__global__ __launch_bounds__(256) void k_out(const unsigned char* __restrict__ Qat,
                                             const unsigned char* __restrict__ AVPt,
                                             const int* __restrict__ mask,
                                             float* __restrict__ out) {
    __shared__ __align__(16) unsigned char As[16384];
    __shared__ __align__(16) unsigned char Bs[16384];
    const int tid = threadIdx.x, l = tid & 63, wid = tid >> 6;
    const int wm = wid >> 1, wn = wid & 1;
    const int g = l >> 4, lr = l & 15;
    const int d = blockIdx.x;
    const int nt = (d >> 3) & 3;
    const int mt = (d & 7) + ((d >> 5) << 3);
    const int m0 = mt * 128, j0 = nt * 128;
    const int b = m0 >> 14;
    f32x4 acc[4][4] = {};

    for (int ks = 0; ks < 4; ++ks) {
        const size_t abase = ((size_t)(mt * 4 + ks)) * 16384;
        const size_t bbase = ((size_t)((b * 4 + nt) * 4 + ks)) * 16384;
#pragma unroll
        for (int i = 0; i < 4; ++i) {
            gl2lds16(Qat + abase + i * 4096 + tid * 16, As + i * 4096 + tid * 16);
            gl2lds16(AVPt + bbase + i * 4096 + tid * 16, Bs + i * 4096 + tid * 16);
        }
        __syncthreads();
        bf16x8 af[4][2];
#pragma unroll
        for (int mf = 0; mf < 4; ++mf) {
            int row = wm * 64 + mf * 16 + lr;
#pragma unroll
            for (int k2 = 0; k2 < 2; ++k2)
                af[mf][k2] = *(const bf16x8*)(As + row * 128 + (((k2 * 4 + g) ^ (row & 7)) << 4));
        }
#pragma unroll
        for (int k2 = 0; k2 < 2; ++k2) {
#pragma unroll
            for (int nf = 0; nf < 4; ++nf) {
                int brow = wn * 64 + nf * 16 + lr;
                bf16x8 bv = *(const bf16x8*)(Bs + brow * 128 + (((k2 * 4 + g) ^ (brow & 7)) << 4));
#pragma unroll
                for (int mf = 0; mf < 4; ++mf)
                    acc[mf][nf] = MFMA16(af[mf][k2], bv, acc[mf][nf]);
            }
        }
        __syncthreads();
    }
#pragma unroll
    for (int mf = 0; mf < 4; ++mf) {
        int trow = m0 + wm * 64 + mf * 16 + g * 4;
#pragma unroll
        for (int r = 0; r < 4; ++r) {
            float mv = (mask[trow + r] > 0) ? 1.0f : 0.0f;
#pragma unroll
            for (int nf = 0; nf < 4; ++nf) {
                int j = j0 + wn * 64 + nf * 16 + lr;
                out[(size_t)(trow + r) * 512 + j] = acc[mf][nf][r] * mv;
            }
        }
    }
}

// ------------------------------- launch -----------------------------------------
extern "C" void kernel_launch(void* const* d_in, const int* in_sizes, int n_in,
                              void* d_out, int out_size, void* d_ws, size_t ws_size,
                              hipStream_t stream) {
    const float* x  = (const float*)d_in[0];
    const int*  mk  = (const int*)d_in[1];
    const float* at = (const float*)d_in[2];
    const float* Wq = (const float*)d_in[3];
    const float* Wk = (const float*)d_in[4];
    const float* Wv = (const float*)d_in[5];
    const float* Wp = (const float*)d_in[6];
    float* out = (float*)d_out;
    char* ws = (char*)d_ws;

    unsigned char*  xt    = (unsigned char*)(ws);                        // [0,64) tiled x (live through k_qkvs)
    float* part_pv = (float*)(ws + ((size_t)64 << 20));                  // [64,98) 33.5 MiB
    float* part_ml = (float*)(ws + ((size_t)100 << 20));                 // [100,101) 1 MiB
    unsigned char*  Qat   = (unsigned char*)(ws + ((size_t)192 << 20));  // [192,224) tiled (not aliasing xt)
    unsigned short* Wpt   = (unsigned short*)(ws + ((size_t)256 << 20)); // [256,256.5)
    unsigned char*  wtl2  = (unsigned char*)(ws + ((size_t)258 << 20));  // [258,259) 1 MiB
    unsigned short* avbf  = (unsigned short*)(ws + ((size_t)259 << 20) + (576 << 10));
    unsigned char*  AVPt  = (unsigned char*)(ws + ((size_t)260 << 20));  // [260,261)

    k_cvt_x<<<16384, 256, 0, stream>>>(x, xt);
    k_w_t_p<<<dim3(16, 16), 256, 0, stream>>>(Wp, Wpt);
    k_w_tile<<<dim3(8, 8), 256, 0, stream>>>(Wv, wtl2);
    k_akw<<<dim3(8, 8, 2), 256, 0, stream>>>(at, Wk, Wq, wtl2);
    k_qkvs<<<4096, 256, 0, stream>>>(xt, wtl2, mk, Qat, part_pv, part_ml);
    k_agent_comb<<<dim3(8, 32), 256, 0, stream>>>(part_pv, part_ml, avbf);
    k_avp<<<32, 64, 0, stream>>>(avbf, Wpt, AVPt);
    k_out<<<2048, 256, 0, stream>>>(Qat, AVPt, mk, out);
}